// Round 9
// baseline (488.509 us; speedup 1.0000x reference)
//
#include <hip/hip_runtime.h>

typedef _Float16 f16;
typedef _Float16 f16x8 __attribute__((ext_vector_type(8)));
typedef float f32x4 __attribute__((ext_vector_type(4)));

#define B_ 2
#define S_ 2048
#define D_ 512
#define H_ 8

__device__ inline void async_ld16(const void* g, void* l) {
  __builtin_amdgcn_global_load_lds((__attribute__((address_space(1))) void*)(g),
                                   (__attribute__((address_space(3))) void*)(l),
                                   16, 0, 0);
}

__global__ __launch_bounds__(256) void cvt_f16(const float* __restrict__ src,
                                               f16* __restrict__ dst, long n) {
  long i = (long)blockIdx.x * 256 + threadIdx.x;
  if (i >= n) return;
  dst[i] = (f16)src[i];
}

// [z][R][C] fp32 -> [z][C][R] fp16
__global__ __launch_bounds__(256) void transpose_f32(const float* __restrict__ src,
                                                     f16* __restrict__ dst, int R, int C) {
  __shared__ float t[32][33];
  size_t zoff = (size_t)blockIdx.z * R * C;
  const float* s = src + zoff;
  int tx = threadIdx.x;
  int ty = threadIdx.y;
  int c0 = blockIdx.x * 32, r0 = blockIdx.y * 32;
#pragma unroll
  for (int i = 0; i < 4; ++i)
    t[ty + i * 8][tx] = s[(size_t)(r0 + ty + i * 8) * C + c0 + tx];
  __syncthreads();
#pragma unroll
  for (int i = 0; i < 4; ++i)
    dst[zoff + (size_t)(c0 + ty + i * 8) * R + r0 + tx] = (f16)t[tx][ty + i * 8];
}

// out[i] = bo[i%D] + sum over nslab split-K partial slabs
__global__ __launch_bounds__(256) void reduce_out(const float* __restrict__ part,
                                                  const float* __restrict__ bo,
                                                  float* __restrict__ out, long n, int nslab) {
  long i = (long)blockIdx.x * 256 + threadIdx.x;
  if (i >= n) return;
  float v = bo[i & (D_ - 1)];
  for (int s = 0; s < nslab; ++s) v += part[(long)s * n + i];
  out[i] = v;
}

struct GemmArgs {
  const f16 *A, *Bm;
  void* C;
  const float* bias;
  float* Mloc;   // PEXP: per-(colblock,row) local max, non-atomic
  int K, lda, ldb, ldc;
  int zbase, NG, PBG;
  long sAp, sAb, sAg, sAz;
  long sBp, sBb, sBg, sBz;
  long sCp, sCb, sCg, sCz;
  long sbp, sbb, sbg, sbz;
  long sMlz;
};

// NT GEMM fp16, fp32 acc — 128x128 2-barrier structure (scores/outproj/fallback).
// PEXP: direct exp-store epilogue (r8: proven; removed LDS repack + 8 barriers).
template <typename OutT, int BIAS, bool PEXP>
__global__ __launch_bounds__(256) void gemm_nt(GemmArgs p) {
  int zloc = blockIdx.z;
  int zi = p.zbase + zloc;
  int pp = zi / p.PBG; int rz = zi - pp * p.PBG;
  int bb = rz / p.NG;  int g = rz - bb * p.NG;
  const f16* A  = p.A + (pp * p.sAp + bb * p.sAb + g * p.sAg + (long)zloc * p.sAz);
  const f16* Bm = p.Bm + (pp * p.sBp + bb * p.sBb + g * p.sBg + (long)zloc * p.sBz);
  OutT* C = (OutT*)p.C + (pp * p.sCp + bb * p.sCb + g * p.sCg + (long)zloc * p.sCz);
  const float* bias = nullptr;
  if (BIAS) bias = p.bias + (pp * p.sbp + bb * p.sbb + g * p.sbg + (long)zloc * p.sbz);

  __shared__ f16 lA[4096];
  __shared__ f16 lB[4096];
  __shared__ float lMx[PEXP ? 256 : 1];

  int tid = threadIdx.x;
  int lane = tid & 63;
  int w = tid >> 6;
  int wm = (w >> 1) << 6;
  int wn = (w & 1) << 6;
  long bm = (long)blockIdx.y * 128;
  long bn = (long)blockIdx.x * 128;

  f32x4 acc[4][4] = {};
  int qd = lane >> 4;
  int fr = lane & 15;

  int q0 = tid, q1 = tid + 256;
  int r0s = q0 >> 2, c0s = (q0 & 3) ^ ((r0s >> 1) & 3);
  int r1s = q1 >> 2, c1s = (q1 & 3) ^ ((r1s >> 1) & 3);

  for (int k0 = 0; k0 < p.K; k0 += 32) {
    long oa0 = (bm + r0s) * (long)p.lda + (k0 + c0s * 8);
    long oa1 = (bm + r1s) * (long)p.lda + (k0 + c1s * 8);
    long ob0 = (bn + r0s) * (long)p.ldb + (k0 + c0s * 8);
    long ob1 = (bn + r1s) * (long)p.ldb + (k0 + c1s * 8);
    __syncthreads();
    async_ld16(A + oa0,  lA + (size_t)q0 * 8);
    async_ld16(A + oa1,  lA + (size_t)q1 * 8);
    async_ld16(Bm + ob0, lB + (size_t)q0 * 8);
    async_ld16(Bm + ob1, lB + (size_t)q1 * 8);
    __syncthreads();

    f16x8 ah[4], bh[4];
#pragma unroll
    for (int i = 0; i < 4; ++i) {
      int m = wm + i * 16 + fr;
      ah[i] = *(const f16x8*)(lA + ((size_t)m * 4 + (qd ^ ((m >> 1) & 3))) * 8);
      int n = wn + i * 16 + fr;
      bh[i] = *(const f16x8*)(lB + ((size_t)n * 4 + (qd ^ ((n >> 1) & 3))) * 8);
    }
#pragma unroll
    for (int i = 0; i < 4; ++i)
#pragma unroll
      for (int j = 0; j < 4; ++j)
        acc[i][j] = __builtin_amdgcn_mfma_f32_16x16x32_f16(ah[i], bh[j], acc[i][j], 0, 0, 0);
  }

  int rr0 = qd * 4;
  if (PEXP) {
#pragma unroll
    for (int i = 0; i < 4; ++i) {
#pragma unroll
      for (int r = 0; r < 4; ++r) {
        float v = fmaxf(fmaxf(acc[i][0][r], acc[i][1][r]),
                        fmaxf(acc[i][2][r], acc[i][3][r]));
        v = fmaxf(v, __shfl_xor(v, 1, 64));
        v = fmaxf(v, __shfl_xor(v, 2, 64));
        v = fmaxf(v, __shfl_xor(v, 4, 64));
        v = fmaxf(v, __shfl_xor(v, 8, 64));
        if (fr == 0) lMx[(w & 1) * 128 + wm + i * 16 + rr0 + r] = v;
      }
    }
    __syncthreads();
    if (tid < 128) {
      float ml = fmaxf(lMx[tid], lMx[128 + tid]);
      p.Mloc[(long)zloc * p.sMlz + (long)blockIdx.x * S_ + bm + tid] = ml;
    }
#pragma unroll
    for (int i = 0; i < 4; ++i) {
#pragma unroll
      for (int r = 0; r < 4; ++r) {
        int rl = wm + i * 16 + rr0 + r;
        float ml = fmaxf(lMx[rl], lMx[128 + rl]);
        long row = bm + rl;
#pragma unroll
        for (int j = 0; j < 4; ++j) {
          long col = bn + wn + j * 16 + fr;
          ((f16*)C)[row * (long)p.ldc + col] = (f16)__expf(acc[i][j][r] - ml);
        }
      }
    }
  } else {
#pragma unroll
    for (int i = 0; i < 4; ++i) {
#pragma unroll
      for (int j = 0; j < 4; ++j) {
#pragma unroll
        for (int r = 0; r < 4; ++r) {
          long row = bm + wm + i * 16 + rr0 + r;
          long col = bn + wn + j * 16 + fr;
          float v = acc[i][j][r];
          if (BIAS == 1) v += bias[col];
          if (BIAS == 2) v += bias[row];
          C[row * (long)p.ldc + col] = (OutT)v;
        }
      }
    }
  }
}

// ---------------------------------------------------------------------------
// r9: fused QKV on the 256x256 8-phase counted-vmcnt template (guide T3+T4+T5).
// 8 waves (2x4), BK=64, LDS 128KB = 2buf x (A,B) x 2 halves of 16KB.
// Phase = one C-quadrant (mh,nh): needs exactly A-half(mh) + B-half(nh).
// Per-tile issue order [A0,B0,B1,A1], one half-tile per phase, 1 tile ahead
// -> steady-state s_waitcnt vmcnt(6) (2 loads x 3 half-tiles in flight),
// never 0 in the main loop. Buffer WAR separated by >=1 barrier (audited).
// Chunk swizzle: slot = c ^ ((row>>1)&7), applied on stage-SOURCE and read
// (involution; gload_lds dest stays linear per guide rule #21).
// ---------------------------------------------------------------------------
struct QkvArgs {
  const f16 *xh, *wqk, *wv;
  f16 *qk, *vT;
  const float *bqk, *bv;
};

template <int MH, int NH>
__device__ inline void phase_mfma(const f16* L, int cur, int qr, int qc,
                                  int qd, int fr, f32x4 (&acc)[2][2][4][2]) {
  const f16* Ab = L + cur * 32768 + MH * 8192;
  const f16* Bb = L + cur * 32768 + 16384 + NH * 8192;
  f16x8 af[4][2], bf[2][2];
#pragma unroll
  for (int i = 0; i < 4; ++i) {
    int rr = qr * 64 + i * 16 + fr;
#pragma unroll
    for (int ks = 0; ks < 2; ++ks) {
      int cc = ks * 4 + qd;
      af[i][ks] = *(const f16x8*)(Ab + ((size_t)rr * 8 + (cc ^ ((rr >> 1) & 7))) * 8);
    }
  }
#pragma unroll
  for (int j = 0; j < 2; ++j) {
    int rr = qc * 32 + j * 16 + fr;
#pragma unroll
    for (int ks = 0; ks < 2; ++ks) {
      int cc = ks * 4 + qd;
      bf[j][ks] = *(const f16x8*)(Bb + ((size_t)rr * 8 + (cc ^ ((rr >> 1) & 7))) * 8);
    }
  }
  __builtin_amdgcn_s_setprio(1);
#pragma unroll
  for (int i = 0; i < 4; ++i)
#pragma unroll
    for (int j = 0; j < 2; ++j)
#pragma unroll
      for (int ks = 0; ks < 2; ++ks)
        acc[MH][NH][i][j] = __builtin_amdgcn_mfma_f32_16x16x32_f16(
            af[i][ks], bf[j][ks], acc[MH][NH][i][j], 0, 0, 0);
  __builtin_amdgcn_s_setprio(0);
}

#define QWAIT(N)                                              \
  asm volatile("s_waitcnt vmcnt(" #N ")" ::: "memory");       \
  __builtin_amdgcn_s_barrier();                               \
  __builtin_amdgcn_sched_barrier(0);
#define QBAR()                                                \
  __builtin_amdgcn_s_barrier();                               \
  __builtin_amdgcn_sched_barrier(0);

__global__ __launch_bounds__(512, 2) void qkv_proj8(QkvArgs p) {
  const long SD = (long)S_ * D_, DD = (long)D_ * D_, DS = (long)D_ * S_;
  int zi = blockIdx.z;
  int pp = zi >> 4;
  int r = zi & 15;
  int b = r >> 3, h = r & 7;
  int bid = blockIdx.x;
  const f16 *A, *Bm;
  f16* C;
  const float* bias;
  long bm, bn;
  int ldc;
  bool biasRow;
  if (pp < 2) {
    A = p.xh + (long)b * SD;
    Bm = p.wqk + ((long)pp * 8 + h) * DD;
    C = p.qk + (long)zi * SD;
    bias = p.bqk + ((long)pp * 8 + h) * D_;
    bm = (long)(bid >> 1) * 256; bn = (long)(bid & 1) * 256;
    ldc = D_; biasRow = false;
  } else {
    A = p.wv + (long)h * DD;
    Bm = p.xh + (long)b * SD;
    C = p.vT + (long)(b * 8 + h) * DS;
    bias = p.bv + (long)h * D_;
    bm = (long)(bid >> 3) * 256; bn = (long)(bid & 7) * 256;
    ldc = S_; biasRow = true;
  }

  __shared__ f16 L[65536];  // 128 KB

  int tid = threadIdx.x;
  int lane = tid & 63;
  int w = tid >> 6;             // 0..7
  int qr = w >> 2, qc = w & 3;  // wave sub-tile within quadrant: 2M x 4N
  int qd = lane >> 4, fr = lane & 15;

  f32x4 acc[2][2][4][2] = {};

  int srl = w * 16 + (lane >> 3);  // staging row base (+ k*8)
  int sslot = lane & 7;

  // Stage one 16KB half-tile (128 rows x 64 k): 2 gload_lds per thread.
  // LDS dest linear; SOURCE chunk pre-swizzled (rule #21).
  auto stage = [&](const f16* src, long row0, int kb, int ldsBase) {
#pragma unroll
    for (int k = 0; k < 2; ++k) {
      int rl = srl + k * 8;
      int c = sslot ^ ((rl >> 1) & 7);
      async_ld16(src + (row0 + rl) * (long)D_ + (kb + c * 8),
                 L + ldsBase + (w * 2 + k) * 512 + lane * 8);
    }
  };
  auto iA = [&](int buf, int hh, int t) {
    stage(A, bm + hh * 128, t * 64, buf * 32768 + hh * 8192);
  };
  auto iB = [&](int buf, int hh, int t) {
    stage(Bm, bn + hh * 128, t * 64, buf * 32768 + 16384 + hh * 8192);
  };

  // prologue: tile 0 half-tiles in order [A0, B0, B1, A1]
  iA(0, 0, 0); iB(0, 0, 0); iB(0, 1, 0); iA(0, 1, 0);

  int cur = 0;
  for (int t = 0; t < 7; ++t) {
    int nxt = cur ^ 1;
    // ph0: Q(0,0) needs A0,B0(t)
    iA(nxt, 0, t + 1);
    QWAIT(6)
    phase_mfma<0, 0>(L, cur, qr, qc, qd, fr, acc);
    // ph1: Q(0,1) needs B1(t)
    iB(nxt, 0, t + 1);
    QWAIT(6)
    phase_mfma<0, 1>(L, cur, qr, qc, qd, fr, acc);
    // ph2: Q(1,0) needs A1(t)
    iB(nxt, 1, t + 1);
    QWAIT(6)
    phase_mfma<1, 0>(L, cur, qr, qc, qd, fr, acc);
    // ph3: Q(1,1) — all halves already waited
    iA(nxt, 1, t + 1);
    QBAR()
    phase_mfma<1, 1>(L, cur, qr, qc, qd, fr, acc);
    cur = nxt;
  }
  // t = 7 (peeled tail, no further issues; drain 4 -> 2 -> 0)
  QWAIT(4)
  phase_mfma<0, 0>(L, cur, qr, qc, qd, fr, acc);
  QWAIT(2)
  phase_mfma<0, 1>(L, cur, qr, qc, qd, fr, acc);
  QWAIT(0)
  phase_mfma<1, 0>(L, cur, qr, qc, qd, fr, acc);
  QBAR()
  phase_mfma<1, 1>(L, cur, qr, qc, qd, fr, acc);

  int rr0 = qd * 4;
#pragma unroll
  for (int mh = 0; mh < 2; ++mh)
#pragma unroll
    for (int nh = 0; nh < 2; ++nh)
#pragma unroll
      for (int i = 0; i < 4; ++i)
#pragma unroll
        for (int j = 0; j < 2; ++j)
#pragma unroll
          for (int rl = 0; rl < 4; ++rl) {
            long row = bm + mh * 128 + qr * 64 + i * 16 + rr0 + rl;
            long col = bn + nh * 128 + qc * 32 + j * 16 + fr;
            float v = acc[mh][nh][i][j][rl] + (biasRow ? bias[row] : bias[col]);
            C[row * (long)ldc + col] = (f16)v;
          }
}

// Flash-PV with pre-exp'd P: O = sum_t P*alpha * V / l.  (frozen from r8)
struct PvArgs {
  const f16* S; const float* Ml; const f16* V; f16* C;
  int ldc, zbase, NG;
  long sVz, sCb, sCg;
};
__global__ __launch_bounds__(256) void pv_flash(PvArgs p) {
  int zloc = blockIdx.z;
  int zi = p.zbase + zloc;
  int bb = zi / p.NG; int g = zi - bb * p.NG;
  const f16* Sm = p.S + (long)zloc * S_ * S_;
  const float* Ml = p.Ml + (long)zloc * 16 * S_;
  const f16* V = p.V + (long)zloc * p.sVz;
  f16* C = p.C + bb * p.sCb + g * p.sCg;

  __shared__ f16 lP[2][64 * 32];
  __shared__ f16 lV[2][128 * 32];

  int tid = threadIdx.x;
  int lane = tid & 63;
  int w = tid >> 6;
  long bm = (long)blockIdx.y * 64;
  long bn = (long)blockIdx.x * 128;
  int e0 = (w & 1) << 6;
  int m0 = (w >> 1) << 5;

  int qd = lane >> 4;
  int fr = lane & 15;

  f32x4 acc[2][4] = {};
  f32x4 lacc[2] = {};
  f16x8 ones;
#pragma unroll
  for (int j = 0; j < 8; ++j) ones[j] = (f16)1.0f;

  float mg[2];
#pragma unroll
  for (int i = 0; i < 2; ++i) {
    float m = -1e30f;
#pragma unroll
    for (int cb = 0; cb < 16; ++cb)
      m = fmaxf(m, Ml[cb * S_ + bm + m0 + i * 16 + fr]);
    mg[i] = m;
  }
  f16 al16[2];

  int rs = tid >> 2, cs = (tid & 3) ^ ((rs >> 1) & 3);

  for (int k0 = 0; k0 < S_; k0 += 64) {
    if ((k0 & 127) == 0) {
      int cb = k0 >> 7;
#pragma unroll
      for (int i = 0; i < 2; ++i)
        al16[i] = (f16)__expf(Ml[cb * S_ + bm + m0 + i * 16 + fr] - mg[i]);
    }
    __syncthreads();
#pragma unroll
    for (int t = 0; t < 2; ++t) {
      async_ld16(Sm + (bm + rs) * (long)S_ + (k0 + t * 32 + cs * 8),
                 lP[t] + (size_t)tid * 8);
#pragma unroll
      for (int j = 0; j < 2; ++j) {
        int q = j * 256 + tid;
        int rv = q >> 2, cv = (q & 3) ^ ((rv >> 1) & 3);
        async_ld16(V + (bn + rv) * (long)S_ + (k0 + t * 32 + cv * 8),
                   lV[t] + (size_t)q * 8);
      }
    }
    __syncthreads();

#pragma unroll
    for (int t = 0; t < 2; ++t) {
      f16x8 ah[2], bh[4];
#pragma unroll
      for (int i = 0; i < 2; ++i) {
        int m = m0 + i * 16 + fr;
        ah[i] = *(const f16x8*)(lP[t] + ((size_t)m * 4 + (qd ^ ((m >> 1) & 3))) * 8);
#pragma unroll
        for (int j = 0; j < 8; ++j) ah[i][j] *= al16[i];
      }
#pragma unroll
      for (int j = 0; j < 4; ++j) {
        int n = e0 + j * 16 + fr;
        bh[j] = *(const f16x8*)(lV[t] + ((size_t)n * 4 + (qd ^ ((n >> 1) & 3))) * 8);
      }
#pragma unroll
      for (int i = 0; i < 2; ++i) {
        lacc[i] = __builtin_amdgcn_mfma_f32_16x16x32_f16(ah[i], ones, lacc[i], 0, 0, 0);
#pragma unroll
        for (int j = 0; j < 4; ++j)
          acc[i][j] = __builtin_amdgcn_mfma_f32_16x16x32_f16(ah[i], bh[j], acc[i][j], 0, 0, 0);
      }
    }
  }

  int rr0 = qd * 4;
#pragma unroll
  for (int i = 0; i < 2; ++i) {
    float inv[4];
#pragma unroll
    for (int r = 0; r < 4; ++r) inv[r] = 1.0f / lacc[i][r];
#pragma unroll
    for (int j = 0; j < 4; ++j) {
#pragma unroll
      for (int r = 0; r < 4; ++r) {
        long row = bm + m0 + i * 16 + rr0 + r;
        long col = bn + e0 + j * 16 + fr;
        C[row * (long)p.ldc + col] = (f16)(acc[i][j][r] * inv[r]);
      }
    }
  }
}

extern "C" void kernel_launch(void* const* d_in, const int* in_sizes, int n_in,
                              void* d_out, int out_size, void* d_ws, size_t ws_size,
                              hipStream_t stream) {
  const float* x  = (const float*)d_in[0];
  const float* Wq = (const float*)d_in[1];
  const float* bq = (const float*)d_in[2];
  const float* Wk = (const float*)d_in[3];
  const float* bk = (const float*)d_in[4];
  const float* Wv = (const float*)d_in[5];
  const float* bv = (const float*)d_in[6];
  const float* Wo = (const float*)d_in[7];
  const float* bo = (const float*)d_in[8];
  float* out = (float*)d_out;

  auto al = [](size_t v) { return (v + 255) & ~(size_t)255; };
  const size_t eX = (size_t)B_ * S_ * D_;
  const size_t eW = (size_t)H_ * D_ * D_;
  const size_t eSS = (size_t)S_ * S_;
  const long SD = (long)S_ * D_;
  const long DD = (long)D_ * D_;
  const long DS = (long)D_ * S_;

  size_t fixed = al(eX * 2) + al(2 * eW * 2) + al(eW * 2) + al(eW * 2)
               + al(2ULL * H_ * D_ * 4);
  int NB = 1, GH = 1, GS = 1; bool found = false;
  for (int nb = 2; nb >= 1 && !found; --nb)
    for (int gh = 8; gh >= 1 && !found; gh >>= 1)
      for (int gs = nb * gh; gs >= 1 && !found; gs >>= 1) {
        size_t need = fixed + al((size_t)nb * S_ * H_ * D_ * 2)
                    + al(2ULL * nb * gh * S_ * D_ * 2)
                    + al((size_t)nb * gh * D_ * S_ * 2)
                    + al(4ULL * nb * SD * 4)
                    + al((size_t)gs * eSS * 2)
                    + al((size_t)gs * 16 * S_ * 4);
        if (need <= ws_size) { NB = nb; GH = gh; GS = gs; found = true; }
      }

  char* p0 = (char*)d_ws;
  size_t off = 0;
  f16* xh    = (f16*)(p0 + off); off += al(eX * 2);
  f16* wqk   = (f16*)(p0 + off); off += al(2 * eW * 2);
  f16* wv    = (f16*)(p0 + off); off += al(eW * 2);
  f16* wo    = (f16*)(p0 + off); off += al(eW * 2);
  float* bqk = (float*)(p0 + off); off += al(2ULL * H_ * D_ * 4);
  f16* catb  = (f16*)(p0 + off); off += al((size_t)NB * S_ * H_ * D_ * 2);
  f16* qk    = (f16*)(p0 + off); off += al(2ULL * NB * GH * S_ * D_ * 2);
  f16* vT    = (f16*)(p0 + off); off += al((size_t)NB * GH * D_ * S_ * 2);
  float* opart = (float*)(p0 + off); off += al(4ULL * NB * SD * 4);
  f16* scores = (f16*)(p0 + off); off += al((size_t)GS * eSS * 2);
  float* mloc = (float*)(p0 + off);

  // ---- prep ----
  cvt_f16<<<dim3((unsigned)((eX + 255) / 256)), 256, 0, stream>>>(x, xh, (long)eX);
  dim3 tb(32, 8, 1);
  transpose_f32<<<dim3(16, 16, H_), tb, 0, stream>>>(Wq, wqk, D_, D_);
  transpose_f32<<<dim3(16, 16, H_), tb, 0, stream>>>(Wk, wqk + eW, D_, D_);
  transpose_f32<<<dim3(16, 16, H_), tb, 0, stream>>>(Wv, wv, D_, D_);
  transpose_f32<<<dim3(16, 128, 1), tb, 0, stream>>>(Wo, wo, H_ * D_, D_);
  hipMemcpyAsync(bqk, bq, (size_t)H_ * D_ * 4, hipMemcpyDeviceToDevice, stream);
  hipMemcpyAsync(bqk + H_ * D_, bk, (size_t)H_ * D_ * 4, hipMemcpyDeviceToDevice, stream);

  for (int b0 = 0; b0 < B_; b0 += NB) {
    for (int h0 = 0; h0 < H_; h0 += GH) {
      if (NB == 2 && GH == 8) {
        QkvArgs a{xh, wqk, wv, qk, vT, bqk, bv};
        qkv_proj8<<<dim3(16, 1, 48), 512, 0, stream>>>(a);
      } else {
        {  // Q+K projections
          GemmArgs a{};
          a.A = xh + (long)b0 * SD;
          a.Bm = wqk + (long)h0 * DD;
          a.C = qk; a.bias = bqk + (long)h0 * D_;
          a.K = D_; a.lda = D_; a.ldb = D_; a.ldc = D_;
          a.zbase = 0; a.NG = GH; a.PBG = NB * GH;
          a.sAb = SD;
          a.sBp = (long)H_ * DD; a.sBg = DD;
          a.sCz = SD;
          a.sbp = (long)H_ * D_; a.sbg = D_;
          gemm_nt<f16, 1, false><<<dim3(4, 16, 2 * NB * GH), 256, 0, stream>>>(a);
        }
        {  // V^T
          GemmArgs a{};
          a.A = wv + (long)h0 * DD; a.Bm = xh + (long)b0 * SD;
          a.C = vT; a.bias = bv + (long)h0 * D_;
          a.K = D_; a.lda = D_; a.ldb = D_; a.ldc = S_;
          a.zbase = 0; a.NG = GH; a.PBG = NB * GH;
          a.sAg = DD;
          a.sBb = SD;
          a.sCz = DS;
          a.sbg = D_;
          gemm_nt<f16, 2, false><<<dim3(16, 4, NB * GH), 256, 0, stream>>>(a);
        }
      }
      for (int g0 = 0; g0 < NB * GH; g0 += GS) {
        {  // scores -> P_loc = exp(s - m_loc) f16, Mloc (no atomics)
          GemmArgs a{};
          a.A = qk + (long)g0 * SD;
          a.Bm = qk + ((long)NB * GH + g0) * SD;
          a.C = scores; a.Mloc = mloc;
          a.K = D_; a.lda = D_; a.ldb = D_; a.ldc = S_;
          a.zbase = g0; a.NG = GH; a.PBG = NB * GH;
          a.sAz = SD; a.sBz = SD; a.sCz = (long)eSS;
          a.sMlz = 16L * S_;
          gemm_nt<f16, 0, true><<<dim3(16, 16, GS), 256, 0, stream>>>(a);
        }
        {  // flash PV (rescale-only, 128-col e-blocks, BK=64)
          PvArgs a{};
          a.S = scores; a.Ml = mloc; a.V = vT + (long)g0 * DS;
          a.C = catb + (long)h0 * D_;
          a.ldc = H_ * D_; a.zbase = g0; a.NG = GH;
          a.sVz = DS; a.sCb = (long)S_ * H_ * D_; a.sCg = D_;
          pv_flash<<<dim3(4, S_ / 64, GS), 256, 0, stream>>>(a);
        }
      }
    }
    {  // out-proj split-K (4 slabs of 1024)
      GemmArgs a{};
      a.A = catb; a.Bm = wo;
      a.C = opart;
      a.K = 1024; a.lda = H_ * D_; a.ldb = H_ * D_; a.ldc = D_;
      a.zbase = 0; a.NG = 4; a.PBG = NB * 4;
      a.sAb = (long)S_ * H_ * D_; a.sAg = 1024;
      a.sBg = 1024;
      a.sCb = SD; a.sCg = (long)NB * SD;
      gemm_nt<float, 0, false><<<dim3(4, 16, NB * 4), 256, 0, stream>>>(a);
    }
    reduce_out<<<dim3((unsigned)(((long)NB * SD + 255) / 256)), 256, 0, stream>>>(
        opart, bo, out + (long)b0 * SD, (long)NB * SD, 4);
  }
}

// Round 11
// 458.269 us; speedup vs baseline: 1.0660x; 1.0660x over previous
//
#include <hip/hip_runtime.h>

typedef _Float16 f16;
typedef _Float16 f16x8 __attribute__((ext_vector_type(8)));
typedef float f32x4 __attribute__((ext_vector_type(4)));

#define B_ 2
#define S_ 2048
#define D_ 512
#define H_ 8

__device__ inline void async_ld16(const void* g, void* l) {
  __builtin_amdgcn_global_load_lds((__attribute__((address_space(1))) void*)(g),
                                   (__attribute__((address_space(3))) void*)(l),
                                   16, 0, 0);
}

__global__ __launch_bounds__(256) void cvt_f16(const float* __restrict__ src,
                                               f16* __restrict__ dst, long n) {
  long i = (long)blockIdx.x * 256 + threadIdx.x;
  if (i >= n) return;
  dst[i] = (f16)src[i];
}

// [z][R][C] fp32 -> [z][C][R] fp16
__global__ __launch_bounds__(256) void transpose_f32(const float* __restrict__ src,
                                                     f16* __restrict__ dst, int R, int C) {
  __shared__ float t[32][33];
  size_t zoff = (size_t)blockIdx.z * R * C;
  const float* s = src + zoff;
  int tx = threadIdx.x;
  int ty = threadIdx.y;
  int c0 = blockIdx.x * 32, r0 = blockIdx.y * 32;
#pragma unroll
  for (int i = 0; i < 4; ++i)
    t[ty + i * 8][tx] = s[(size_t)(r0 + ty + i * 8) * C + c0 + tx];
  __syncthreads();
#pragma unroll
  for (int i = 0; i < 4; ++i)
    dst[zoff + (size_t)(c0 + ty + i * 8) * R + r0 + tx] = (f16)t[tx][ty + i * 8];
}

// out[i] = bo[i%D] + sum over nslab split-K partial slabs
__global__ __launch_bounds__(256) void reduce_out(const float* __restrict__ part,
                                                  const float* __restrict__ bo,
                                                  float* __restrict__ out, long n, int nslab) {
  long i = (long)blockIdx.x * 256 + threadIdx.x;
  if (i >= n) return;
  float v = bo[i & (D_ - 1)];
  for (int s = 0; s < nslab; ++s) v += part[(long)s * n + i];
  out[i] = v;
}

struct GemmArgs {
  const f16 *A, *Bm;
  void* C;
  const float* bias;
  float* Mloc;
  int K, lda, ldb, ldc;
  int zbase, NG, PBG;
  long sAp, sAb, sAg, sAz;
  long sBp, sBb, sBg, sBz;
  long sCp, sCb, sCg, sCz;
  long sbp, sbb, sbg, sbz;
  long sMlz;
};

// NT GEMM fp16, fp32 acc — 128x128 2-barrier structure (outproj/fallback).
template <typename OutT, int BIAS, bool PEXP>
__global__ __launch_bounds__(256) void gemm_nt(GemmArgs p) {
  int zloc = blockIdx.z;
  int zi = p.zbase + zloc;
  int pp = zi / p.PBG; int rz = zi - pp * p.PBG;
  int bb = rz / p.NG;  int g = rz - bb * p.NG;
  const f16* A  = p.A + (pp * p.sAp + bb * p.sAb + g * p.sAg + (long)zloc * p.sAz);
  const f16* Bm = p.Bm + (pp * p.sBp + bb * p.sBb + g * p.sBg + (long)zloc * p.sBz);
  OutT* C = (OutT*)p.C + (pp * p.sCp + bb * p.sCb + g * p.sCg + (long)zloc * p.sCz);
  const float* bias = nullptr;
  if (BIAS) bias = p.bias + (pp * p.sbp + bb * p.sbb + g * p.sbg + (long)zloc * p.sbz);

  __shared__ f16 lA[4096];
  __shared__ f16 lB[4096];
  __shared__ float lMx[PEXP ? 256 : 1];

  int tid = threadIdx.x;
  int lane = tid & 63;
  int w = tid >> 6;
  int wm = (w >> 1) << 6;
  int wn = (w & 1) << 6;
  long bm = (long)blockIdx.y * 128;
  long bn = (long)blockIdx.x * 128;

  f32x4 acc[4][4] = {};
  int qd = lane >> 4;
  int fr = lane & 15;

  int q0 = tid, q1 = tid + 256;
  int r0s = q0 >> 2, c0s = (q0 & 3) ^ ((r0s >> 1) & 3);
  int r1s = q1 >> 2, c1s = (q1 & 3) ^ ((r1s >> 1) & 3);

  for (int k0 = 0; k0 < p.K; k0 += 32) {
    long oa0 = (bm + r0s) * (long)p.lda + (k0 + c0s * 8);
    long oa1 = (bm + r1s) * (long)p.lda + (k0 + c1s * 8);
    long ob0 = (bn + r0s) * (long)p.ldb + (k0 + c0s * 8);
    long ob1 = (bn + r1s) * (long)p.ldb + (k0 + c1s * 8);
    __syncthreads();
    async_ld16(A + oa0,  lA + (size_t)q0 * 8);
    async_ld16(A + oa1,  lA + (size_t)q1 * 8);
    async_ld16(Bm + ob0, lB + (size_t)q0 * 8);
    async_ld16(Bm + ob1, lB + (size_t)q1 * 8);
    __syncthreads();

    f16x8 ah[4], bh[4];
#pragma unroll
    for (int i = 0; i < 4; ++i) {
      int m = wm + i * 16 + fr;
      ah[i] = *(const f16x8*)(lA + ((size_t)m * 4 + (qd ^ ((m >> 1) & 3))) * 8);
      int n = wn + i * 16 + fr;
      bh[i] = *(const f16x8*)(lB + ((size_t)n * 4 + (qd ^ ((n >> 1) & 3))) * 8);
    }
#pragma unroll
    for (int i = 0; i < 4; ++i)
#pragma unroll
      for (int j = 0; j < 4; ++j)
        acc[i][j] = __builtin_amdgcn_mfma_f32_16x16x32_f16(ah[i], bh[j], acc[i][j], 0, 0, 0);
  }

  int rr0 = qd * 4;
  if (PEXP) {
#pragma unroll
    for (int i = 0; i < 4; ++i) {
#pragma unroll
      for (int r = 0; r < 4; ++r) {
        float v = fmaxf(fmaxf(acc[i][0][r], acc[i][1][r]),
                        fmaxf(acc[i][2][r], acc[i][3][r]));
        v = fmaxf(v, __shfl_xor(v, 1, 64));
        v = fmaxf(v, __shfl_xor(v, 2, 64));
        v = fmaxf(v, __shfl_xor(v, 4, 64));
        v = fmaxf(v, __shfl_xor(v, 8, 64));
        if (fr == 0) lMx[(w & 1) * 128 + wm + i * 16 + rr0 + r] = v;
      }
    }
    __syncthreads();
    if (tid < 128) {
      float ml = fmaxf(lMx[tid], lMx[128 + tid]);
      p.Mloc[(long)zloc * p.sMlz + (long)blockIdx.x * S_ + bm + tid] = ml;
    }
#pragma unroll
    for (int i = 0; i < 4; ++i) {
#pragma unroll
      for (int r = 0; r < 4; ++r) {
        int rl = wm + i * 16 + rr0 + r;
        float ml = fmaxf(lMx[rl], lMx[128 + rl]);
        long row = bm + rl;
#pragma unroll
        for (int j = 0; j < 4; ++j) {
          long col = bn + wn + j * 16 + fr;
          ((f16*)C)[row * (long)p.ldc + col] = (f16)__expf(acc[i][j][r] - ml);
        }
      }
    }
  } else {
#pragma unroll
    for (int i = 0; i < 4; ++i) {
#pragma unroll
      for (int j = 0; j < 4; ++j) {
#pragma unroll
        for (int r = 0; r < 4; ++r) {
          long row = bm + wm + i * 16 + rr0 + r;
          long col = bn + wn + j * 16 + fr;
          float v = acc[i][j][r];
          if (BIAS == 1) v += bias[col];
          if (BIAS == 2) v += bias[row];
          C[row * (long)p.ldc + col] = (OutT)v;
        }
      }
    }
  }
}

// ---------------------------------------------------------------------------
// 256x256 8-phase counted-vmcnt template (T3+T4+T5) — r9-verified in qkv8.
// ---------------------------------------------------------------------------
struct QkvArgs {
  const f16 *xh, *wqk, *wv;
  f16 *qk, *vT;
  const float *bqk, *bv;
};

template <int MH, int NH>
__device__ inline void phase_mfma(const f16* L, int cur, int qr, int qc,
                                  int qd, int fr, f32x4 (&acc)[2][2][4][2]) {
  const f16* Ab = L + cur * 32768 + MH * 8192;
  const f16* Bb = L + cur * 32768 + 16384 + NH * 8192;
  f16x8 af[4][2], bf[2][2];
#pragma unroll
  for (int i = 0; i < 4; ++i) {
    int rr = qr * 64 + i * 16 + fr;
#pragma unroll
    for (int ks = 0; ks < 2; ++ks) {
      int cc = ks * 4 + qd;
      af[i][ks] = *(const f16x8*)(Ab + ((size_t)rr * 8 + (cc ^ ((rr >> 1) & 7))) * 8);
    }
  }
#pragma unroll
  for (int j = 0; j < 2; ++j) {
    int rr = qc * 32 + j * 16 + fr;
#pragma unroll
    for (int ks = 0; ks < 2; ++ks) {
      int cc = ks * 4 + qd;
      bf[j][ks] = *(const f16x8*)(Bb + ((size_t)rr * 8 + (cc ^ ((rr >> 1) & 7))) * 8);
    }
  }
  __builtin_amdgcn_s_setprio(1);
#pragma unroll
  for (int i = 0; i < 4; ++i)
#pragma unroll
    for (int j = 0; j < 2; ++j)
#pragma unroll
      for (int ks = 0; ks < 2; ++ks)
        acc[MH][NH][i][j] = __builtin_amdgcn_mfma_f32_16x16x32_f16(
            af[i][ks], bf[j][ks], acc[MH][NH][i][j], 0, 0, 0);
  __builtin_amdgcn_s_setprio(0);
}

#define QWAIT(N)                                              \
  asm volatile("s_waitcnt vmcnt(" #N ")" ::: "memory");       \
  __builtin_amdgcn_s_barrier();                               \
  __builtin_amdgcn_sched_barrier(0);
#define QBAR()                                                \
  __builtin_amdgcn_s_barrier();                               \
  __builtin_amdgcn_sched_barrier(0);

__global__ __launch_bounds__(512, 2) void qkv_proj8(QkvArgs p) {
  const long SD = (long)S_ * D_, DD = (long)D_ * D_, DS = (long)D_ * S_;
  int zi = blockIdx.z;
  int pp = zi >> 4;
  int r = zi & 15;
  int b = r >> 3, h = r & 7;
  int bid = blockIdx.x;
  const f16 *A, *Bm;
  f16* C;
  const float* bias;
  long bm, bn;
  int ldc;
  bool biasRow;
  if (pp < 2) {
    A = p.xh + (long)b * SD;
    Bm = p.wqk + ((long)pp * 8 + h) * DD;
    C = p.qk + (long)zi * SD;
    bias = p.bqk + ((long)pp * 8 + h) * D_;
    bm = (long)(bid >> 1) * 256; bn = (long)(bid & 1) * 256;
    ldc = D_; biasRow = false;
  } else {
    A = p.wv + (long)h * DD;
    Bm = p.xh + (long)b * SD;
    C = p.vT + (long)(b * 8 + h) * DS;
    bias = p.bv + (long)h * D_;
    bm = (long)(bid >> 3) * 256; bn = (long)(bid & 7) * 256;
    ldc = S_; biasRow = true;
  }

  __shared__ f16 L[65536];  // 128 KB

  int tid = threadIdx.x;
  int lane = tid & 63;
  int w = tid >> 6;
  int qr = w >> 2, qc = w & 3;
  int qd = lane >> 4, fr = lane & 15;

  f32x4 acc[2][2][4][2] = {};

  int srl = w * 16 + (lane >> 3);
  int sslot = lane & 7;

  auto stage = [&](const f16* src, long row0, int kb, int ldsBase) {
#pragma unroll
    for (int k = 0; k < 2; ++k) {
      int rl = srl + k * 8;
      int c = sslot ^ ((rl >> 1) & 7);
      async_ld16(src + (row0 + rl) * (long)D_ + (kb + c * 8),
                 L + ldsBase + (w * 2 + k) * 512 + lane * 8);
    }
  };
  auto iA = [&](int buf, int hh, int t) {
    stage(A, bm + hh * 128, t * 64, buf * 32768 + hh * 8192);
  };
  auto iB = [&](int buf, int hh, int t) {
    stage(Bm, bn + hh * 128, t * 64, buf * 32768 + 16384 + hh * 8192);
  };

  iA(0, 0, 0); iB(0, 0, 0); iB(0, 1, 0); iA(0, 1, 0);

  int cur = 0;
  for (int t = 0; t < 7; ++t) {
    int nxt = cur ^ 1;
    iA(nxt, 0, t + 1);
    QWAIT(6)
    phase_mfma<0, 0>(L, cur, qr, qc, qd, fr, acc);
    iB(nxt, 0, t + 1);
    QWAIT(6)
    phase_mfma<0, 1>(L, cur, qr, qc, qd, fr, acc);
    iB(nxt, 1, t + 1);
    QWAIT(6)
    phase_mfma<1, 0>(L, cur, qr, qc, qd, fr, acc);
    iA(nxt, 1, t + 1);
    QBAR()
    phase_mfma<1, 1>(L, cur, qr, qc, qd, fr, acc);
    cur = nxt;
  }
  QWAIT(4)
  phase_mfma<0, 0>(L, cur, qr, qc, qd, fr, acc);
  QWAIT(2)
  phase_mfma<0, 1>(L, cur, qr, qc, qd, fr, acc);
  QWAIT(0)
  phase_mfma<1, 0>(L, cur, qr, qc, qd, fr, acc);
  QBAR()
  phase_mfma<1, 1>(L, cur, qr, qc, qd, fr, acc);

  int rr0 = qd * 4;
#pragma unroll
  for (int mh = 0; mh < 2; ++mh)
#pragma unroll
    for (int nh = 0; nh < 2; ++nh)
#pragma unroll
      for (int i = 0; i < 4; ++i)
#pragma unroll
        for (int j = 0; j < 2; ++j)
#pragma unroll
          for (int rl = 0; rl < 4; ++rl) {
            long row = bm + mh * 128 + qr * 64 + i * 16 + rr0 + rl;
            long col = bn + nh * 128 + qc * 32 + j * 16 + fr;
            float v = acc[mh][nh][i][j][rl] + (biasRow ? bias[row] : bias[col]);
            C[row * (long)ldc + col] = (f16)v;
          }
}

// ---------------------------------------------------------------------------
// scores on the 8-phase template. C = Q·K^T per z; PEXP epilogue:
// per-wave row-max over its 64 cols (shfl over fr), cross-wave combine via
// lMx2[qc][256], 256-col max written to BOTH 128-col Mloc slots (pv exact:
// P*alpha = exp(s-ml)*exp(ml-mg)); direct exp-stores (r8-proven pattern).
// ---------------------------------------------------------------------------
struct Sc8Args {
  const f16 *Q, *K;
  f16* P;
  float* Ml;
};

__global__ __launch_bounds__(512, 2) void scores8(Sc8Args p) {
  int zloc = blockIdx.z;
  const f16* A  = p.Q + (long)zloc * S_ * D_;
  const f16* Bm = p.K + (long)zloc * S_ * D_;
  f16* C = p.P + (long)zloc * (long)S_ * S_;
  float* Ml = p.Ml + (long)zloc * 16L * S_;
  int bid = blockIdx.x;
  long bm = (long)(bid >> 3) * 256, bn = (long)(bid & 7) * 256;

  __shared__ f16 L[65536];        // 128 KB
  __shared__ float lMx2[4][256];  // 4 KB per-wave-col row maxes

  int tid = threadIdx.x;
  int lane = tid & 63;
  int w = tid >> 6;
  int qr = w >> 2, qc = w & 3;
  int qd = lane >> 4, fr = lane & 15;

  f32x4 acc[2][2][4][2] = {};

  int srl = w * 16 + (lane >> 3);
  int sslot = lane & 7;

  auto stage = [&](const f16* src, long row0, int kb, int ldsBase) {
#pragma unroll
    for (int k = 0; k < 2; ++k) {
      int rl = srl + k * 8;
      int c = sslot ^ ((rl >> 1) & 7);
      async_ld16(src + (row0 + rl) * (long)D_ + (kb + c * 8),
                 L + ldsBase + (w * 2 + k) * 512 + lane * 8);
    }
  };
  auto iA = [&](int buf, int hh, int t) {
    stage(A, bm + hh * 128, t * 64, buf * 32768 + hh * 8192);
  };
  auto iB = [&](int buf, int hh, int t) {
    stage(Bm, bn + hh * 128, t * 64, buf * 32768 + 16384 + hh * 8192);
  };

  iA(0, 0, 0); iB(0, 0, 0); iB(0, 1, 0); iA(0, 1, 0);

  int cur = 0;
  for (int t = 0; t < 7; ++t) {
    int nxt = cur ^ 1;
    iA(nxt, 0, t + 1);
    QWAIT(6)
    phase_mfma<0, 0>(L, cur, qr, qc, qd, fr, acc);
    iB(nxt, 0, t + 1);
    QWAIT(6)
    phase_mfma<0, 1>(L, cur, qr, qc, qd, fr, acc);
    iB(nxt, 1, t + 1);
    QWAIT(6)
    phase_mfma<1, 0>(L, cur, qr, qc, qd, fr, acc);
    iA(nxt, 1, t + 1);
    QBAR()
    phase_mfma<1, 1>(L, cur, qr, qc, qd, fr, acc);
    cur = nxt;
  }
  QWAIT(4)
  phase_mfma<0, 0>(L, cur, qr, qc, qd, fr, acc);
  QWAIT(2)
  phase_mfma<0, 1>(L, cur, qr, qc, qd, fr, acc);
  QWAIT(0)
  phase_mfma<1, 0>(L, cur, qr, qc, qd, fr, acc);
  QBAR()
  phase_mfma<1, 1>(L, cur, qr, qc, qd, fr, acc);

  // --- PEXP epilogue ---
#pragma unroll
  for (int mh = 0; mh < 2; ++mh)
#pragma unroll
    for (int i = 0; i < 4; ++i)
#pragma unroll
      for (int rl = 0; rl < 4; ++rl) {
        float v = fmaxf(fmaxf(acc[mh][0][i][0][rl], acc[mh][0][i][1][rl]),
                        fmaxf(acc[mh][1][i][0][rl], acc[mh][1][i][1][rl]));
        v = fmaxf(v, __shfl_xor(v, 1, 64));
        v = fmaxf(v, __shfl_xor(v, 2, 64));
        v = fmaxf(v, __shfl_xor(v, 4, 64));
        v = fmaxf(v, __shfl_xor(v, 8, 64));
        if (fr == 0) lMx2[qc][mh * 128 + qr * 64 + i * 16 + qd * 4 + rl] = v;
      }
  __syncthreads();
  if (tid < 256) {
    float ml = fmaxf(fmaxf(lMx2[0][tid], lMx2[1][tid]),
                     fmaxf(lMx2[2][tid], lMx2[3][tid]));
    int cb0 = (bid & 7) * 2;
    Ml[(long)cb0 * S_ + bm + tid] = ml;
    Ml[(long)(cb0 + 1) * S_ + bm + tid] = ml;
  }
#pragma unroll
  for (int mh = 0; mh < 2; ++mh)
#pragma unroll
    for (int i = 0; i < 4; ++i)
#pragma unroll
      for (int rl = 0; rl < 4; ++rl) {
        int rowLoc = mh * 128 + qr * 64 + i * 16 + qd * 4 + rl;
        float ml = fmaxf(fmaxf(lMx2[0][rowLoc], lMx2[1][rowLoc]),
                         fmaxf(lMx2[2][rowLoc], lMx2[3][rowLoc]));
        long row = bm + rowLoc;
#pragma unroll
        for (int nh = 0; nh < 2; ++nh)
#pragma unroll
          for (int j = 0; j < 2; ++j) {
            long col = bn + nh * 128 + qc * 32 + j * 16 + fr;
            C[row * (long)S_ + col] = (f16)__expf(acc[mh][nh][i][j][rl] - ml);
          }
      }
}

// Flash-PV with pre-exp'd P: O = sum_t P*alpha * V / l.  (frozen from r8)
struct PvArgs {
  const f16* S; const float* Ml; const f16* V; f16* C;
  int ldc, zbase, NG;
  long sVz, sCb, sCg;
};
__global__ __launch_bounds__(256) void pv_flash(PvArgs p) {
  int zloc = blockIdx.z;
  int zi = p.zbase + zloc;
  int bb = zi / p.NG; int g = zi - bb * p.NG;
  const f16* Sm = p.S + (long)zloc * S_ * S_;
  const float* Ml = p.Ml + (long)zloc * 16 * S_;
  const f16* V = p.V + (long)zloc * p.sVz;
  f16* C = p.C + bb * p.sCb + g * p.sCg;

  __shared__ f16 lP[2][64 * 32];
  __shared__ f16 lV[2][128 * 32];

  int tid = threadIdx.x;
  int lane = tid & 63;
  int w = tid >> 6;
  long bm = (long)blockIdx.y * 64;
  long bn = (long)blockIdx.x * 128;
  int e0 = (w & 1) << 6;
  int m0 = (w >> 1) << 5;

  int qd = lane >> 4;
  int fr = lane & 15;

  f32x4 acc[2][4] = {};
  f32x4 lacc[2] = {};
  f16x8 ones;
#pragma unroll
  for (int j = 0; j < 8; ++j) ones[j] = (f16)1.0f;

  float mg[2];
#pragma unroll
  for (int i = 0; i < 2; ++i) {
    float m = -1e30f;
#pragma unroll
    for (int cb = 0; cb < 16; ++cb)
      m = fmaxf(m, Ml[cb * S_ + bm + m0 + i * 16 + fr]);
    mg[i] = m;
  }
  f16 al16[2];

  int rs = tid >> 2, cs = (tid & 3) ^ ((rs >> 1) & 3);

  for (int k0 = 0; k0 < S_; k0 += 64) {
    if ((k0 & 127) == 0) {
      int cb = k0 >> 7;
#pragma unroll
      for (int i = 0; i < 2; ++i)
        al16[i] = (f16)__expf(Ml[cb * S_ + bm + m0 + i * 16 + fr] - mg[i]);
    }
    __syncthreads();
#pragma unroll
    for (int t = 0; t < 2; ++t) {
      async_ld16(Sm + (bm + rs) * (long)S_ + (k0 + t * 32 + cs * 8),
                 lP[t] + (size_t)tid * 8);
#pragma unroll
      for (int j = 0; j < 2; ++j) {
        int q = j * 256 + tid;
        int rv = q >> 2, cv = (q & 3) ^ ((rv >> 1) & 3);
        async_ld16(V + (bn + rv) * (long)S_ + (k0 + t * 32 + cv * 8),
                   lV[t] + (size_t)q * 8);
      }
    }
    __syncthreads();

#pragma unroll
    for (int t = 0; t < 2; ++t) {
      f16x8 ah[2], bh[4];
#pragma unroll
      for (int i = 0; i < 2; ++i) {
        int m = m0 + i * 16 + fr;
        ah[i] = *(const f16x8*)(lP[t] + ((size_t)m * 4 + (qd ^ ((m >> 1) & 3))) * 8);
#pragma unroll
        for (int j = 0; j < 8; ++j) ah[i][j] *= al16[i];
      }
#pragma unroll
      for (int j = 0; j < 4; ++j) {
        int n = e0 + j * 16 + fr;
        bh[j] = *(const f16x8*)(lV[t] + ((size_t)n * 4 + (qd ^ ((n >> 1) & 3))) * 8);
      }
#pragma unroll
      for (int i = 0; i < 2; ++i) {
        lacc[i] = __builtin_amdgcn_mfma_f32_16x16x32_f16(ah[i], ones, lacc[i], 0, 0, 0);
#pragma unroll
        for (int j = 0; j < 4; ++j)
          acc[i][j] = __builtin_amdgcn_mfma_f32_16x16x32_f16(ah[i], bh[j], acc[i][j], 0, 0, 0);
      }
    }
  }

  int rr0 = qd * 4;
#pragma unroll
  for (int i = 0; i < 2; ++i) {
    float inv[4];
#pragma unroll
    for (int r = 0; r < 4; ++r) inv[r] = 1.0f / lacc[i][r];
#pragma unroll
    for (int j = 0; j < 4; ++j) {
#pragma unroll
      for (int r = 0; r < 4; ++r) {
        long row = bm + m0 + i * 16 + rr0 + r;
        long col = bn + e0 + j * 16 + fr;
        C[row * (long)p.ldc + col] = (f16)(acc[i][j][r] * inv[r]);
      }
    }
  }
}

extern "C" void kernel_launch(void* const* d_in, const int* in_sizes, int n_in,
                              void* d_out, int out_size, void* d_ws, size_t ws_size,
                              hipStream_t stream) {
  const float* x  = (const float*)d_in[0];
  const float* Wq = (const float*)d_in[1];
  const float* bq = (const float*)d_in[2];
  const float* Wk = (const float*)d_in[3];
  const float* bk = (const float*)d_in[4];
  const float* Wv = (const float*)d_in[5];
  const float* bv = (const float*)d_in[6];
  const float* Wo = (const float*)d_in[7];
  const float* bo = (const float*)d_in[8];
  float* out = (float*)d_out;

  auto al = [](size_t v) { return (v + 255) & ~(size_t)255; };
  const size_t eX = (size_t)B_ * S_ * D_;
  const size_t eW = (size_t)H_ * D_ * D_;
  const size_t eSS = (size_t)S_ * S_;
  const long SD = (long)S_ * D_;
  const long DD = (long)D_ * D_;
  const long DS = (long)D_ * S_;

  size_t fixed = al(eX * 2) + al(2 * eW * 2) + al(eW * 2) + al(eW * 2)
               + al(2ULL * H_ * D_ * 4);
  int NB = 1, GH = 1, GS = 1; bool found = false;
  for (int nb = 2; nb >= 1 && !found; --nb)
    for (int gh = 8; gh >= 1 && !found; gh >>= 1)
      for (int gs = nb * gh; gs >= 1 && !found; gs >>= 1) {
        size_t need = fixed + al((size_t)nb * S_ * H_ * D_ * 2)
                    + al(2ULL * nb * gh * S_ * D_ * 2)
                    + al((size_t)nb * gh * D_ * S_ * 2)
                    + al(4ULL * nb * SD * 4)
                    + al((size_t)gs * eSS * 2)
                    + al((size_t)gs * 16 * S_ * 4);
        if (need <= ws_size) { NB = nb; GH = gh; GS = gs; found = true; }
      }

  char* p0 = (char*)d_ws;
  size_t off = 0;
  f16* xh    = (f16*)(p0 + off); off += al(eX * 2);
  f16* wqk   = (f16*)(p0 + off); off += al(2 * eW * 2);
  f16* wv    = (f16*)(p0 + off); off += al(eW * 2);
  f16* wo    = (f16*)(p0 + off); off += al(eW * 2);
  float* bqk = (float*)(p0 + off); off += al(2ULL * H_ * D_ * 4);
  f16* catb  = (f16*)(p0 + off); off += al((size_t)NB * S_ * H_ * D_ * 2);
  f16* qk    = (f16*)(p0 + off); off += al(2ULL * NB * GH * S_ * D_ * 2);
  f16* vT    = (f16*)(p0 + off); off += al((size_t)NB * GH * D_ * S_ * 2);
  float* opart = (float*)(p0 + off); off += al(4ULL * NB * SD * 4);
  f16* scores = (f16*)(p0 + off); off += al((size_t)GS * eSS * 2);
  float* mloc = (float*)(p0 + off);

  // ---- prep ----
  cvt_f16<<<dim3((unsigned)((eX + 255) / 256)), 256, 0, stream>>>(x, xh, (long)eX);
  dim3 tb(32, 8, 1);
  transpose_f32<<<dim3(16, 16, H_), tb, 0, stream>>>(Wq, wqk, D_, D_);
  transpose_f32<<<dim3(16, 16, H_), tb, 0, stream>>>(Wk, wqk + eW, D_, D_);
  transpose_f32<<<dim3(16, 16, H_), tb, 0, stream>>>(Wv, wv, D_, D_);
  transpose_f32<<<dim3(16, 128, 1), tb, 0, stream>>>(Wo, wo, H_ * D_, D_);
  hipMemcpyAsync(bqk, bq, (size_t)H_ * D_ * 4, hipMemcpyDeviceToDevice, stream);
  hipMemcpyAsync(bqk + H_ * D_, bk, (size_t)H_ * D_ * 4, hipMemcpyDeviceToDevice, stream);

  for (int b0 = 0; b0 < B_; b0 += NB) {
    for (int h0 = 0; h0 < H_; h0 += GH) {
      if (NB == 2 && GH == 8) {
        QkvArgs a{xh, wqk, wv, qk, vT, bqk, bv};
        qkv_proj8<<<dim3(16, 1, 48), 512, 0, stream>>>(a);
      } else {
        {  // Q+K projections
          GemmArgs a{};
          a.A = xh + (long)b0 * SD;
          a.Bm = wqk + (long)h0 * DD;
          a.C = qk; a.bias = bqk + (long)h0 * D_;
          a.K = D_; a.lda = D_; a.ldb = D_; a.ldc = D_;
          a.zbase = 0; a.NG = GH; a.PBG = NB * GH;
          a.sAb = SD;
          a.sBp = (long)H_ * DD; a.sBg = DD;
          a.sCz = SD;
          a.sbp = (long)H_ * D_; a.sbg = D_;
          gemm_nt<f16, 1, false><<<dim3(4, 16, 2 * NB * GH), 256, 0, stream>>>(a);
        }
        {  // V^T
          GemmArgs a{};
          a.A = wv + (long)h0 * DD; a.Bm = xh + (long)b0 * SD;
          a.C = vT; a.bias = bv + (long)h0 * D_;
          a.K = D_; a.lda = D_; a.ldb = D_; a.ldc = S_;
          a.zbase = 0; a.NG = GH; a.PBG = NB * GH;
          a.sAg = DD;
          a.sBb = SD;
          a.sCz = DS;
          a.sbg = D_;
          gemm_nt<f16, 2, false><<<dim3(16, 4, NB * GH), 256, 0, stream>>>(a);
        }
      }
      for (int g0 = 0; g0 < NB * GH; g0 += GS) {
        {  // scores -> P = exp(s - ml256) f16, Mloc (8-phase template)
          Sc8Args a{qk + (long)g0 * SD, qk + ((long)NB * GH + g0) * SD,
                    scores, mloc};
          scores8<<<dim3(64, 1, GS), 512, 0, stream>>>(a);
        }
        {  // flash PV (rescale-only, 128-col e-blocks, BK=64)
          PvArgs a{};
          a.S = scores; a.Ml = mloc; a.V = vT + (long)g0 * DS;
          a.C = catb + (long)h0 * D_;
          a.ldc = H_ * D_; a.zbase = g0; a.NG = GH;
          a.sVz = DS; a.sCb = (long)S_ * H_ * D_; a.sCg = D_;
          pv_flash<<<dim3(4, S_ / 64, GS), 256, 0, stream>>>(a);
        }
      }
    }
    {  // out-proj split-K (4 slabs of 1024)
      GemmArgs a{};
      a.A = catb; a.Bm = wo;
      a.C = opart;
      a.K = 1024; a.lda = H_ * D_; a.ldb = H_ * D_; a.ldc = D_;
      a.zbase = 0; a.NG = 4; a.PBG = NB * 4;
      a.sAb = (long)S_ * H_ * D_; a.sAg = 1024;
      a.sBg = 1024;
      a.sCb = SD; a.sCg = (long)NB * SD;
      gemm_nt<float, 0, false><<<dim3(4, 16, NB * 4), 256, 0, stream>>>(a);
    }
    reduce_out<<<dim3((unsigned)(((long)NB * SD + 255) / 256)), 256, 0, stream>>>(
        opart, bo, out + (long)b0 * SD, (long)NB * SD, 4);
  }
}

// Round 15
// 457.795 us; speedup vs baseline: 1.0671x; 1.0010x over previous
//
#include <hip/hip_runtime.h>

typedef _Float16 f16;
typedef _Float16 f16x8 __attribute__((ext_vector_type(8)));
typedef float f32x4 __attribute__((ext_vector_type(4)));

#define B_ 2
#define S_ 2048
#define D_ 512
#define H_ 8

__device__ inline void async_ld16(const void* g, void* l) {
  __builtin_amdgcn_global_load_lds((__attribute__((address_space(1))) void*)(g),
                                   (__attribute__((address_space(3))) void*)(l),
                                   16, 0, 0);
}

__global__ __launch_bounds__(256) void cvt_f16(const float* __restrict__ src,
                                               f16* __restrict__ dst, long n) {
  long i = (long)blockIdx.x * 256 + threadIdx.x;
  if (i >= n) return;
  dst[i] = (f16)src[i];
}

// [z][R][C] fp32 -> [z][C][R] fp16
__global__ __launch_bounds__(256) void transpose_f32(const float* __restrict__ src,
                                                     f16* __restrict__ dst, int R, int C) {
  __shared__ float t[32][33];
  size_t zoff = (size_t)blockIdx.z * R * C;
  const float* s = src + zoff;
  int tx = threadIdx.x;
  int ty = threadIdx.y;
  int c0 = blockIdx.x * 32, r0 = blockIdx.y * 32;
#pragma unroll
  for (int i = 0; i < 4; ++i)
    t[ty + i * 8][tx] = s[(size_t)(r0 + ty + i * 8) * C + c0 + tx];
  __syncthreads();
#pragma unroll
  for (int i = 0; i < 4; ++i)
    dst[zoff + (size_t)(c0 + ty + i * 8) * R + r0 + tx] = (f16)t[tx][ty + i * 8];
}

// out[i] = bo[i%D] + sum over nslab split-K partial slabs
__global__ __launch_bounds__(256) void reduce_out(const float* __restrict__ part,
                                                  const float* __restrict__ bo,
                                                  float* __restrict__ out, long n, int nslab) {
  long i = (long)blockIdx.x * 256 + threadIdx.x;
  if (i >= n) return;
  float v = bo[i & (D_ - 1)];
  for (int s = 0; s < nslab; ++s) v += part[(long)s * n + i];
  out[i] = v;
}

struct GemmArgs {
  const f16 *A, *Bm;
  void* C;
  const float* bias;
  float* Mloc;
  int K, lda, ldb, ldc;
  int zbase, NG, PBG;
  long sAp, sAb, sAg, sAz;
  long sBp, sBb, sBg, sBz;
  long sCp, sCb, sCg, sCz;
  long sbp, sbb, sbg, sbz;
  long sMlz;
};

// NT GEMM fp16, fp32 acc — 128x128 2-barrier structure (outproj/fallback).
template <typename OutT, int BIAS, bool PEXP>
__global__ __launch_bounds__(256) void gemm_nt(GemmArgs p) {
  int zloc = blockIdx.z;
  int zi = p.zbase + zloc;
  int pp = zi / p.PBG; int rz = zi - pp * p.PBG;
  int bb = rz / p.NG;  int g = rz - bb * p.NG;
  const f16* A  = p.A + (pp * p.sAp + bb * p.sAb + g * p.sAg + (long)zloc * p.sAz);
  const f16* Bm = p.Bm + (pp * p.sBp + bb * p.sBb + g * p.sBg + (long)zloc * p.sBz);
  OutT* C = (OutT*)p.C + (pp * p.sCp + bb * p.sCb + g * p.sCg + (long)zloc * p.sCz);
  const float* bias = nullptr;
  if (BIAS) bias = p.bias + (pp * p.sbp + bb * p.sbb + g * p.sbg + (long)zloc * p.sbz);

  __shared__ f16 lA[4096];
  __shared__ f16 lB[4096];
  __shared__ float lMx[PEXP ? 256 : 1];

  int tid = threadIdx.x;
  int lane = tid & 63;
  int w = tid >> 6;
  int wm = (w >> 1) << 6;
  int wn = (w & 1) << 6;
  long bm = (long)blockIdx.y * 128;
  long bn = (long)blockIdx.x * 128;

  f32x4 acc[4][4] = {};
  int qd = lane >> 4;
  int fr = lane & 15;

  int q0 = tid, q1 = tid + 256;
  int r0s = q0 >> 2, c0s = (q0 & 3) ^ ((r0s >> 1) & 3);
  int r1s = q1 >> 2, c1s = (q1 & 3) ^ ((r1s >> 1) & 3);

  for (int k0 = 0; k0 < p.K; k0 += 32) {
    long oa0 = (bm + r0s) * (long)p.lda + (k0 + c0s * 8);
    long oa1 = (bm + r1s) * (long)p.lda + (k0 + c1s * 8);
    long ob0 = (bn + r0s) * (long)p.ldb + (k0 + c0s * 8);
    long ob1 = (bn + r1s) * (long)p.ldb + (k0 + c1s * 8);
    __syncthreads();
    async_ld16(A + oa0,  lA + (size_t)q0 * 8);
    async_ld16(A + oa1,  lA + (size_t)q1 * 8);
    async_ld16(Bm + ob0, lB + (size_t)q0 * 8);
    async_ld16(Bm + ob1, lB + (size_t)q1 * 8);
    __syncthreads();

    f16x8 ah[4], bh[4];
#pragma unroll
    for (int i = 0; i < 4; ++i) {
      int m = wm + i * 16 + fr;
      ah[i] = *(const f16x8*)(lA + ((size_t)m * 4 + (qd ^ ((m >> 1) & 3))) * 8);
      int n = wn + i * 16 + fr;
      bh[i] = *(const f16x8*)(lB + ((size_t)n * 4 + (qd ^ ((n >> 1) & 3))) * 8);
    }
#pragma unroll
    for (int i = 0; i < 4; ++i)
#pragma unroll
      for (int j = 0; j < 4; ++j)
        acc[i][j] = __builtin_amdgcn_mfma_f32_16x16x32_f16(ah[i], bh[j], acc[i][j], 0, 0, 0);
  }

  int rr0 = qd * 4;
  if (PEXP) {
#pragma unroll
    for (int i = 0; i < 4; ++i) {
#pragma unroll
      for (int r = 0; r < 4; ++r) {
        float v = fmaxf(fmaxf(acc[i][0][r], acc[i][1][r]),
                        fmaxf(acc[i][2][r], acc[i][3][r]));
        v = fmaxf(v, __shfl_xor(v, 1, 64));
        v = fmaxf(v, __shfl_xor(v, 2, 64));
        v = fmaxf(v, __shfl_xor(v, 4, 64));
        v = fmaxf(v, __shfl_xor(v, 8, 64));
        if (fr == 0) lMx[(w & 1) * 128 + wm + i * 16 + rr0 + r] = v;
      }
    }
    __syncthreads();
    if (tid < 128) {
      float ml = fmaxf(lMx[tid], lMx[128 + tid]);
      p.Mloc[(long)zloc * p.sMlz + (long)blockIdx.x * S_ + bm + tid] = ml;
    }
#pragma unroll
    for (int i = 0; i < 4; ++i) {
#pragma unroll
      for (int r = 0; r < 4; ++r) {
        int rl = wm + i * 16 + rr0 + r;
        float ml = fmaxf(lMx[rl], lMx[128 + rl]);
        long row = bm + rl;
#pragma unroll
        for (int j = 0; j < 4; ++j) {
          long col = bn + wn + j * 16 + fr;
          ((f16*)C)[row * (long)p.ldc + col] = (f16)__expf(acc[i][j][r] - ml);
        }
      }
    }
  } else {
#pragma unroll
    for (int i = 0; i < 4; ++i) {
#pragma unroll
      for (int j = 0; j < 4; ++j) {
#pragma unroll
        for (int r = 0; r < 4; ++r) {
          long row = bm + wm + i * 16 + rr0 + r;
          long col = bn + wn + j * 16 + fr;
          float v = acc[i][j][r];
          if (BIAS == 1) v += bias[col];
          if (BIAS == 2) v += bias[row];
          C[row * (long)p.ldc + col] = (OutT)v;
        }
      }
    }
  }
}

// ---------------------------------------------------------------------------
// 256x256 8-phase counted-vmcnt template (T3+T4+T5) — r9/r11-verified.
// ---------------------------------------------------------------------------
struct QkvArgs {
  const f16 *xh, *wqk, *wv;
  f16 *qk, *vT;
  const float *bqk, *bv;
};

template <int MH, int NH>
__device__ inline void phase_mfma(const f16* L, int cur, int qr, int qc,
                                  int qd, int fr, f32x4 (&acc)[2][2][4][2]) {
  const f16* Ab = L + cur * 32768 + MH * 8192;
  const f16* Bb = L + cur * 32768 + 16384 + NH * 8192;
  f16x8 af[4][2], bf[2][2];
#pragma unroll
  for (int i = 0; i < 4; ++i) {
    int rr = qr * 64 + i * 16 + fr;
#pragma unroll
    for (int ks = 0; ks < 2; ++ks) {
      int cc = ks * 4 + qd;
      af[i][ks] = *(const f16x8*)(Ab + ((size_t)rr * 8 + (cc ^ ((rr >> 1) & 7))) * 8);
    }
  }
#pragma unroll
  for (int j = 0; j < 2; ++j) {
    int rr = qc * 32 + j * 16 + fr;
#pragma unroll
    for (int ks = 0; ks < 2; ++ks) {
      int cc = ks * 4 + qd;
      bf[j][ks] = *(const f16x8*)(Bb + ((size_t)rr * 8 + (cc ^ ((rr >> 1) & 7))) * 8);
    }
  }
  __builtin_amdgcn_s_setprio(1);
#pragma unroll
  for (int i = 0; i < 4; ++i)
#pragma unroll
    for (int j = 0; j < 2; ++j)
#pragma unroll
      for (int ks = 0; ks < 2; ++ks)
        acc[MH][NH][i][j] = __builtin_amdgcn_mfma_f32_16x16x32_f16(
            af[i][ks], bf[j][ks], acc[MH][NH][i][j], 0, 0, 0);
  __builtin_amdgcn_s_setprio(0);
}

#define QWAIT(N)                                              \
  asm volatile("s_waitcnt vmcnt(" #N ")" ::: "memory");       \
  __builtin_amdgcn_s_barrier();                               \
  __builtin_amdgcn_sched_barrier(0);
#define QBAR()                                                \
  __builtin_amdgcn_s_barrier();                               \
  __builtin_amdgcn_sched_barrier(0);

__global__ __launch_bounds__(512, 2) void qkv_proj8(QkvArgs p) {
  const long SD = (long)S_ * D_, DD = (long)D_ * D_, DS = (long)D_ * S_;
  int zi = blockIdx.z;
  int pp = zi >> 4;
  int r = zi & 15;
  int b = r >> 3, h = r & 7;
  int bid = blockIdx.x;
  const f16 *A, *Bm;
  f16* C;
  const float* bias;
  long bm, bn;
  int ldc;
  bool biasRow;
  if (pp < 2) {
    A = p.xh + (long)b * SD;
    Bm = p.wqk + ((long)pp * 8 + h) * DD;
    C = p.qk + (long)zi * SD;
    bias = p.bqk + ((long)pp * 8 + h) * D_;
    bm = (long)(bid >> 1) * 256; bn = (long)(bid & 1) * 256;
    ldc = D_; biasRow = false;
  } else {
    A = p.wv + (long)h * DD;
    Bm = p.xh + (long)b * SD;
    C = p.vT + (long)(b * 8 + h) * DS;
    bias = p.bv + (long)h * D_;
    bm = (long)(bid >> 3) * 256; bn = (long)(bid & 7) * 256;
    ldc = S_; biasRow = true;
  }

  __shared__ f16 L[65536];  // 128 KB

  int tid = threadIdx.x;
  int lane = tid & 63;
  int w = tid >> 6;
  int qr = w >> 2, qc = w & 3;
  int qd = lane >> 4, fr = lane & 15;

  f32x4 acc[2][2][4][2] = {};

  int srl = w * 16 + (lane >> 3);
  int sslot = lane & 7;

  auto stage = [&](const f16* src, long row0, int kb, int ldsBase) {
#pragma unroll
    for (int k = 0; k < 2; ++k) {
      int rl = srl + k * 8;
      int c = sslot ^ ((rl >> 1) & 7);
      async_ld16(src + (row0 + rl) * (long)D_ + (kb + c * 8),
                 L + ldsBase + (w * 2 + k) * 512 + lane * 8);
    }
  };
  auto iA = [&](int buf, int hh, int t) {
    stage(A, bm + hh * 128, t * 64, buf * 32768 + hh * 8192);
  };
  auto iB = [&](int buf, int hh, int t) {
    stage(Bm, bn + hh * 128, t * 64, buf * 32768 + 16384 + hh * 8192);
  };

  iA(0, 0, 0); iB(0, 0, 0); iB(0, 1, 0); iA(0, 1, 0);

  int cur = 0;
  for (int t = 0; t < 7; ++t) {
    int nxt = cur ^ 1;
    iA(nxt, 0, t + 1);
    QWAIT(6)
    phase_mfma<0, 0>(L, cur, qr, qc, qd, fr, acc);
    iB(nxt, 0, t + 1);
    QWAIT(6)
    phase_mfma<0, 1>(L, cur, qr, qc, qd, fr, acc);
    iB(nxt, 1, t + 1);
    QWAIT(6)
    phase_mfma<1, 0>(L, cur, qr, qc, qd, fr, acc);
    iA(nxt, 1, t + 1);
    QBAR()
    phase_mfma<1, 1>(L, cur, qr, qc, qd, fr, acc);
    cur = nxt;
  }
  QWAIT(4)
  phase_mfma<0, 0>(L, cur, qr, qc, qd, fr, acc);
  QWAIT(2)
  phase_mfma<0, 1>(L, cur, qr, qc, qd, fr, acc);
  QWAIT(0)
  phase_mfma<1, 0>(L, cur, qr, qc, qd, fr, acc);
  QBAR()
  phase_mfma<1, 1>(L, cur, qr, qc, qd, fr, acc);

  int rr0 = qd * 4;
#pragma unroll
  for (int mh = 0; mh < 2; ++mh)
#pragma unroll
    for (int nh = 0; nh < 2; ++nh)
#pragma unroll
      for (int i = 0; i < 4; ++i)
#pragma unroll
        for (int j = 0; j < 2; ++j)
#pragma unroll
          for (int rl = 0; rl < 4; ++rl) {
            long row = bm + mh * 128 + qr * 64 + i * 16 + rr0 + rl;
            long col = bn + nh * 128 + qc * 32 + j * 16 + fr;
            float v = acc[mh][nh][i][j][rl] + (biasRow ? bias[row] : bias[col]);
            C[row * (long)ldc + col] = (f16)v;
          }
}

// ---------------------------------------------------------------------------
// scores on the 8-phase template (r11-verified).
// ---------------------------------------------------------------------------
struct Sc8Args {
  const f16 *Q, *K;
  f16* P;
  float* Ml;
};

__global__ __launch_bounds__(512, 2) void scores8(Sc8Args p) {
  int zloc = blockIdx.z;
  const f16* A  = p.Q + (long)zloc * S_ * D_;
  const f16* Bm = p.K + (long)zloc * S_ * D_;
  f16* C = p.P + (long)zloc * (long)S_ * S_;
  float* Ml = p.Ml + (long)zloc * 16L * S_;
  int bid = blockIdx.x;
  long bm = (long)(bid >> 3) * 256, bn = (long)(bid & 7) * 256;

  __shared__ f16 L[65536];        // 128 KB
  __shared__ float lMx2[4][256];  // 4 KB per-wave-col row maxes

  int tid = threadIdx.x;
  int lane = tid & 63;
  int w = tid >> 6;
  int qr = w >> 2, qc = w & 3;
  int qd = lane >> 4, fr = lane & 15;

  f32x4 acc[2][2][4][2] = {};

  int srl = w * 16 + (lane >> 3);
  int sslot = lane & 7;

  auto stage = [&](const f16* src, long row0, int kb, int ldsBase) {
#pragma unroll
    for (int k = 0; k < 2; ++k) {
      int rl = srl + k * 8;
      int c = sslot ^ ((rl >> 1) & 7);
      async_ld16(src + (row0 + rl) * (long)D_ + (kb + c * 8),
                 L + ldsBase + (w * 2 + k) * 512 + lane * 8);
    }
  };
  auto iA = [&](int buf, int hh, int t) {
    stage(A, bm + hh * 128, t * 64, buf * 32768 + hh * 8192);
  };
  auto iB = [&](int buf, int hh, int t) {
    stage(Bm, bn + hh * 128, t * 64, buf * 32768 + 16384 + hh * 8192);
  };

  iA(0, 0, 0); iB(0, 0, 0); iB(0, 1, 0); iA(0, 1, 0);

  int cur = 0;
  for (int t = 0; t < 7; ++t) {
    int nxt = cur ^ 1;
    iA(nxt, 0, t + 1);
    QWAIT(6)
    phase_mfma<0, 0>(L, cur, qr, qc, qd, fr, acc);
    iB(nxt, 0, t + 1);
    QWAIT(6)
    phase_mfma<0, 1>(L, cur, qr, qc, qd, fr, acc);
    iB(nxt, 1, t + 1);
    QWAIT(6)
    phase_mfma<1, 0>(L, cur, qr, qc, qd, fr, acc);
    iA(nxt, 1, t + 1);
    QBAR()
    phase_mfma<1, 1>(L, cur, qr, qc, qd, fr, acc);
    cur = nxt;
  }
  QWAIT(4)
  phase_mfma<0, 0>(L, cur, qr, qc, qd, fr, acc);
  QWAIT(2)
  phase_mfma<0, 1>(L, cur, qr, qc, qd, fr, acc);
  QWAIT(0)
  phase_mfma<1, 0>(L, cur, qr, qc, qd, fr, acc);
  QBAR()
  phase_mfma<1, 1>(L, cur, qr, qc, qd, fr, acc);

  // --- PEXP epilogue ---
#pragma unroll
  for (int mh = 0; mh < 2; ++mh)
#pragma unroll
    for (int i = 0; i < 4; ++i)
#pragma unroll
      for (int rl = 0; rl < 4; ++rl) {
        float v = fmaxf(fmaxf(acc[mh][0][i][0][rl], acc[mh][0][i][1][rl]),
                        fmaxf(acc[mh][1][i][0][rl], acc[mh][1][i][1][rl]));
        v = fmaxf(v, __shfl_xor(v, 1, 64));
        v = fmaxf(v, __shfl_xor(v, 2, 64));
        v = fmaxf(v, __shfl_xor(v, 4, 64));
        v = fmaxf(v, __shfl_xor(v, 8, 64));
        if (fr == 0) lMx2[qc][mh * 128 + qr * 64 + i * 16 + qd * 4 + rl] = v;
      }
  __syncthreads();
  if (tid < 256) {
    float ml = fmaxf(fmaxf(lMx2[0][tid], lMx2[1][tid]),
                     fmaxf(lMx2[2][tid], lMx2[3][tid]));
    int cb0 = (bid & 7) * 2;
    Ml[(long)cb0 * S_ + bm + tid] = ml;
    Ml[(long)(cb0 + 1) * S_ + bm + tid] = ml;
  }
#pragma unroll
  for (int mh = 0; mh < 2; ++mh)
#pragma unroll
    for (int i = 0; i < 4; ++i)
#pragma unroll
      for (int rl = 0; rl < 4; ++rl) {
        int rowLoc = mh * 128 + qr * 64 + i * 16 + qd * 4 + rl;
        float ml = fmaxf(fmaxf(lMx2[0][rowLoc], lMx2[1][rowLoc]),
                         fmaxf(lMx2[2][rowLoc], lMx2[3][rowLoc]));
        long row = bm + rowLoc;
#pragma unroll
        for (int nh = 0; nh < 2; ++nh)
#pragma unroll
          for (int j = 0; j < 2; ++j) {
            long col = bn + nh * 128 + qc * 32 + j * 16 + fr;
            C[row * (long)S_ + col] = (f16)__expf(acc[mh][nh][i][j][rl] - ml);
          }
      }
}

// ---------------------------------------------------------------------------
// flash-PV on the 8-phase template — Ml-staging FIX (the r12/r13 NaN):
// gload_lds LDS dest must be wave-uniform base + lane*16B (guide m104/m108).
// Old code used per-lane stride 32B -> half of lMl unwritten -> garbage mg ->
// al=0, lacc=0 -> 0*inf = NaN. Now: row cb = k*8+w (wave-uniform), dest
// lMl + cb*1024B + lane*16B, src MlG + cb*S + bm + lane*4 floats.
// Keeps r13's WAR-safe issue order (iB/iA1 after ph<0>; QWAIT 4/6).
// ---------------------------------------------------------------------------
struct PvArgs {
  const f16* S; const float* Ml; const f16* V; f16* C;
  int ldc, zbase, NG;
  long sVz, sCb, sCg;
};

template <int MH>
__device__ inline void pv_phase(const f16* L, int cur, int qr, int qc, int qd,
                                int fr, const f16 (&al)[2][4],
                                f32x4 (&acc)[2][4][2], f32x4 (&lacc)[2][4],
                                f16x8 ones) {
  const f16* Ab = L + cur * 24576 + MH * 8192;
  const f16* Bb = L + cur * 24576 + 16384;
  f16x8 af[4][2], bf[2][2];
#pragma unroll
  for (int i = 0; i < 4; ++i) {
    int rr = qr * 64 + i * 16 + fr;
#pragma unroll
    for (int ks = 0; ks < 2; ++ks) {
      int cc = ks * 4 + qd;
      af[i][ks] = *(const f16x8*)(Ab + ((size_t)rr * 8 + (cc ^ ((rr >> 1) & 7))) * 8);
#pragma unroll
      for (int e = 0; e < 8; ++e) af[i][ks][e] *= al[MH][i];
    }
  }
#pragma unroll
  for (int j = 0; j < 2; ++j) {
    int rr = qc * 32 + j * 16 + fr;
#pragma unroll
    for (int ks = 0; ks < 2; ++ks) {
      int cc = ks * 4 + qd;
      bf[j][ks] = *(const f16x8*)(Bb + ((size_t)rr * 8 + (cc ^ ((rr >> 1) & 7))) * 8);
    }
  }
  __builtin_amdgcn_s_setprio(1);
#pragma unroll
  for (int i = 0; i < 4; ++i) {
    f16x8 a2 = af[i][0] + af[i][1];
    lacc[MH][i] = __builtin_amdgcn_mfma_f32_16x16x32_f16(a2, ones, lacc[MH][i], 0, 0, 0);
#pragma unroll
    for (int j = 0; j < 2; ++j)
#pragma unroll
      for (int ks = 0; ks < 2; ++ks)
        acc[MH][i][j] = __builtin_amdgcn_mfma_f32_16x16x32_f16(
            af[i][ks], bf[j][ks], acc[MH][i][j], 0, 0, 0);
  }
  __builtin_amdgcn_s_setprio(0);
}

__global__ __launch_bounds__(512, 2) void pv_flash8(PvArgs p) {
  int zloc = blockIdx.z;
  int zi = p.zbase + zloc;
  int bb = zi / p.NG; int g = zi - bb * p.NG;
  const f16* Sm = p.S + (long)zloc * S_ * S_;
  const float* MlG = p.Ml + (long)zloc * 16 * S_;
  const f16* V = p.V + (long)zloc * p.sVz;
  f16* C = p.C + bb * p.sCb + g * p.sCg;

  __shared__ f16 L[49152];     // 96 KB: 2 bufs x (A0,A1,B of 8K f16 each)
  __shared__ float lMl[4096];  // 16 KB: [cb][256 rows]

  int tid = threadIdx.x;
  int lane = tid & 63;
  int w = tid >> 6;
  int qr = w >> 2, qc = w & 3;
  int qd = lane >> 4, fr = lane & 15;

  int bid = blockIdx.x;
  long bm = (long)(bid >> 2) * 256;
  long bn = (long)(bid & 3) * 128;

  f32x4 acc[2][4][2] = {};
  f32x4 lacc[2][4] = {};
  f16x8 ones;
#pragma unroll
  for (int e = 0; e < 8; ++e) ones[e] = (f16)1.0f;

  int srl = w * 16 + (lane >> 3);
  int sslot = lane & 7;

  auto stage = [&](const f16* src, long row0, int kb, int ldsBase) {
#pragma unroll
    for (int k = 0; k < 2; ++k) {
      int rl = srl + k * 8;
      int c = sslot ^ ((rl >> 1) & 7);
      async_ld16(src + (row0 + rl) * (long)S_ + (kb + c * 8),
                 L + ldsBase + (w * 2 + k) * 512 + lane * 8);
    }
  };
  auto iA = [&](int buf, int hh, int t) {
    stage(Sm, bm + hh * 128, t * 64, buf * 24576 + hh * 8192);
  };
  auto iB = [&](int buf, int t) {
    stage(V, bn, t * 64, buf * 24576 + 16384);
  };

  // Prologue: stage Ml slab [16 cb][bm..bm+255] into LDS.
  // dest = wave-uniform base (cb*1024B) + lane*16B; row cb = k*8 + w.
#pragma unroll
  for (int k = 0; k < 2; ++k) {
    int cb = k * 8 + w;
    async_ld16(MlG + (long)cb * S_ + bm + lane * 4,
               (char*)lMl + (size_t)cb * 1024 + (size_t)lane * 16);
  }
  iA(0, 0, 0); iB(0, 0); iA(0, 1, 0);
  asm volatile("s_waitcnt vmcnt(6)" ::: "memory");
  __builtin_amdgcn_s_barrier();

  // mg over 16 cb from LDS; al for cb=0.
  float mg[2][4];
  f16 al[2][4];
#pragma unroll
  for (int mh = 0; mh < 2; ++mh)
#pragma unroll
    for (int i = 0; i < 4; ++i) {
      int rloc = mh * 128 + qr * 64 + i * 16 + fr;
      float m = -1e30f;
#pragma unroll
      for (int cb = 0; cb < 16; ++cb)
        m = fmaxf(m, lMl[cb * 256 + rloc]);
      mg[mh][i] = m;
      al[mh][i] = (f16)__expf(lMl[rloc] - m);
    }

  int cur = 0;
  for (int t = 0; t < 31; ++t) {
    int nxt = cur ^ 1;
    if (t && (t & 1) == 0) {
      int cb = t >> 1;
#pragma unroll
      for (int mh = 0; mh < 2; ++mh)
#pragma unroll
        for (int i = 0; i < 4; ++i) {
          int rloc = mh * 128 + qr * 64 + i * 16 + fr;
          al[mh][i] = (f16)__expf(lMl[cb * 256 + rloc] - mg[mh][i]);
        }
    }
    iA(nxt, 0, t + 1);
    QWAIT(4)                     // drains A0(t)+B(t)
    pv_phase<0>(L, cur, qr, qc, qd, fr, al, acc, lacc, ones);
    iB(nxt, t + 1);
    iA(nxt, 1, t + 1);           // B/A1 writes behind ph<0>'s barrier
    QWAIT(6)                     // drains A1(t)
    pv_phase<1>(L, cur, qr, qc, qd, fr, al, acc, lacc, ones);
    cur = nxt;
  }
  {  // t = 31 tail
    int cb = 15;
#pragma unroll
    for (int mh = 0; mh < 2; ++mh)
#pragma unroll
      for (int i = 0; i < 4; ++i) {
        int rloc = mh * 128 + qr * 64 + i * 16 + fr;
        al[mh][i] = (f16)__expf(lMl[cb * 256 + rloc] - mg[mh][i]);
      }
  }
  QWAIT(2)
  pv_phase<0>(L, cur, qr, qc, qd, fr, al, acc, lacc, ones);
  QWAIT(0)
  pv_phase<1>(L, cur, qr, qc, qd, fr, al, acc, lacc, ones);

  int rr0 = qd * 4;
#pragma unroll
  for (int mh = 0; mh < 2; ++mh)
#pragma unroll
    for (int i = 0; i < 4; ++i) {
      float inv[4];
#pragma unroll
      for (int rl = 0; rl < 4; ++rl) inv[rl] = 1.0f / lacc[mh][i][rl];
#pragma unroll
      for (int j = 0; j < 2; ++j)
#pragma unroll
        for (int rl = 0; rl < 4; ++rl) {
          long row = bm + mh * 128 + qr * 64 + i * 16 + rr0 + rl;
          long col = bn + qc * 32 + j * 16 + fr;
          C[row * (long)p.ldc + col] = (f16)(acc[mh][i][j][rl] * inv[rl]);
        }
    }
}

extern "C" void kernel_launch(void* const* d_in, const int* in_sizes, int n_in,
                              void* d_out, int out_size, void* d_ws, size_t ws_size,
                              hipStream_t stream) {
  const float* x  = (const float*)d_in[0];
  const float* Wq = (const float*)d_in[1];
  const float* bq = (const float*)d_in[2];
  const float* Wk = (const float*)d_in[3];
  const float* bk = (const float*)d_in[4];
  const float* Wv = (const float*)d_in[5];
  const float* bv = (const float*)d_in[6];
  const float* Wo = (const float*)d_in[7];
  const float* bo = (const float*)d_in[8];
  float* out = (float*)d_out;

  auto al = [](size_t v) { return (v + 255) & ~(size_t)255; };
  const size_t eX = (size_t)B_ * S_ * D_;
  const size_t eW = (size_t)H_ * D_ * D_;
  const size_t eSS = (size_t)S_ * S_;
  const long SD = (long)S_ * D_;
  const long DD = (long)D_ * D_;
  const long DS = (long)D_ * S_;

  size_t fixed = al(eX * 2) + al(2 * eW * 2) + al(eW * 2) + al(eW * 2)
               + al(2ULL * H_ * D_ * 4);
  int NB = 1, GH = 1, GS = 1; bool found = false;
  for (int nb = 2; nb >= 1 && !found; --nb)
    for (int gh = 8; gh >= 1 && !found; gh >>= 1)
      for (int gs = nb * gh; gs >= 1 && !found; gs >>= 1) {
        size_t need = fixed + al((size_t)nb * S_ * H_ * D_ * 2)
                    + al(2ULL * nb * gh * S_ * D_ * 2)
                    + al((size_t)nb * gh * D_ * S_ * 2)
                    + al(4ULL * nb * SD * 4)
                    + al((size_t)gs * eSS * 2)
                    + al((size_t)gs * 16 * S_ * 4);
        if (need <= ws_size) { NB = nb; GH = gh; GS = gs; found = true; }
      }

  char* p0 = (char*)d_ws;
  size_t off = 0;
  f16* xh    = (f16*)(p0 + off); off += al(eX * 2);
  f16* wqk   = (f16*)(p0 + off); off += al(2 * eW * 2);
  f16* wv    = (f16*)(p0 + off); off += al(eW * 2);
  f16* wo    = (f16*)(p0 + off); off += al(eW * 2);
  float* bqk = (float*)(p0 + off); off += al(2ULL * H_ * D_ * 4);
  f16* catb  = (f16*)(p0 + off); off += al((size_t)NB * S_ * H_ * D_ * 2);
  f16* qk    = (f16*)(p0 + off); off += al(2ULL * NB * GH * S_ * D_ * 2);
  f16* vT    = (f16*)(p0 + off); off += al((size_t)NB * GH * D_ * S_ * 2);
  float* opart = (float*)(p0 + off); off += al(4ULL * NB * SD * 4);
  f16* scores = (f16*)(p0 + off); off += al((size_t)GS * eSS * 2);
  float* mloc = (float*)(p0 + off);

  // ---- prep ----
  cvt_f16<<<dim3((unsigned)((eX + 255) / 256)), 256, 0, stream>>>(x, xh, (long)eX);
  dim3 tb(32, 8, 1);
  transpose_f32<<<dim3(16, 16, H_), tb, 0, stream>>>(Wq, wqk, D_, D_);
  transpose_f32<<<dim3(16, 16, H_), tb, 0, stream>>>(Wk, wqk + eW, D_, D_);
  transpose_f32<<<dim3(16, 16, H_), tb, 0, stream>>>(Wv, wv, D_, D_);
  transpose_f32<<<dim3(16, 128, 1), tb, 0, stream>>>(Wo, wo, H_ * D_, D_);
  hipMemcpyAsync(bqk, bq, (size_t)H_ * D_ * 4, hipMemcpyDeviceToDevice, stream);
  hipMemcpyAsync(bqk + H_ * D_, bk, (size_t)H_ * D_ * 4, hipMemcpyDeviceToDevice, stream);

  for (int b0 = 0; b0 < B_; b0 += NB) {
    for (int h0 = 0; h0 < H_; h0 += GH) {
      if (NB == 2 && GH == 8) {
        QkvArgs a{xh, wqk, wv, qk, vT, bqk, bv};
        qkv_proj8<<<dim3(16, 1, 48), 512, 0, stream>>>(a);
      } else {
        {  // Q+K projections
          GemmArgs a{};
          a.A = xh + (long)b0 * SD;
          a.Bm = wqk + (long)h0 * DD;
          a.C = qk; a.bias = bqk + (long)h0 * D_;
          a.K = D_; a.lda = D_; a.ldb = D_; a.ldc = D_;
          a.zbase = 0; a.NG = GH; a.PBG = NB * GH;
          a.sAb = SD;
          a.sBp = (long)H_ * DD; a.sBg = DD;
          a.sCz = SD;
          a.sbp = (long)H_ * D_; a.sbg = D_;
          gemm_nt<f16, 1, false><<<dim3(4, 16, 2 * NB * GH), 256, 0, stream>>>(a);
        }
        {  // V^T
          GemmArgs a{};
          a.A = wv + (long)h0 * DD; a.Bm = xh + (long)b0 * SD;
          a.C = vT; a.bias = bv + (long)h0 * D_;
          a.K = D_; a.lda = D_; a.ldb = D_; a.ldc = S_;
          a.zbase = 0; a.NG = GH; a.PBG = NB * GH;
          a.sAg = DD;
          a.sBb = SD;
          a.sCz = DS;
          a.sbg = D_;
          gemm_nt<f16, 2, false><<<dim3(16, 4, NB * GH), 256, 0, stream>>>(a);
        }
      }
      for (int g0 = 0; g0 < NB * GH; g0 += GS) {
        {  // scores -> P = exp(s - ml256) f16, Mloc (8-phase template)
          Sc8Args a{qk + (long)g0 * SD, qk + ((long)NB * GH + g0) * SD,
                    scores, mloc};
          scores8<<<dim3(64, 1, GS), 512, 0, stream>>>(a);
        }
        {  // flash PV on the 8-phase template (256x128, 32-tile pipeline)
          PvArgs a{};
          a.S = scores; a.Ml = mloc; a.V = vT + (long)g0 * DS;
          a.C = catb + (long)h0 * D_;
          a.ldc = H_ * D_; a.zbase = g0; a.NG = GH;
          a.sVz = DS; a.sCb = (long)S_ * H_ * D_; a.sCg = D_;
          pv_flash8<<<dim3(32, 1, GS), 512, 0, stream>>>(a);
        }
      }
    }
    {  // out-proj split-K (4 slabs of 1024)
      GemmArgs a{};
      a.A = catb; a.Bm = wo;
      a.C = opart;
      a.K = 1024; a.lda = H_ * D_; a.ldb = H_ * D_; a.ldc = D_;
      a.zbase = 0; a.NG = 4; a.PBG = NB * 4;
      a.sAb = (long)S_ * H_ * D_; a.sAg = 1024;
      a.sBg = 1024;
      a.sCb = SD; a.sCg = (long)NB * SD;
      gemm_nt<float, 0, false><<<dim3(4, 16, NB * 4), 256, 0, stream>>>(a);
    }
    reduce_out<<<dim3((unsigned)(((long)NB * SD + 255) / 256)), 256, 0, stream>>>(
        opart, bo, out + (long)b0 * SD, (long)NB * SD, 4);
  }
}

// Round 16
// 451.534 us; speedup vs baseline: 1.0819x; 1.0139x over previous
//
#include <hip/hip_runtime.h>

typedef _Float16 f16;
typedef _Float16 f16x8 __attribute__((ext_vector_type(8)));
typedef float f32x4 __attribute__((ext_vector_type(4)));

#define B_ 2
#define S_ 2048
#define D_ 512
#define H_ 8

__device__ inline void async_ld16(const void* g, void* l) {
  __builtin_amdgcn_global_load_lds((__attribute__((address_space(1))) void*)(g),
                                   (__attribute__((address_space(3))) void*)(l),
                                   16, 0, 0);
}

__global__ __launch_bounds__(256) void cvt_f16(const float* __restrict__ src,
                                               f16* __restrict__ dst, long n) {
  long i = (long)blockIdx.x * 256 + threadIdx.x;
  if (i >= n) return;
  dst[i] = (f16)src[i];
}

// [z][R][C] fp32 -> [z][C][R] fp16
__global__ __launch_bounds__(256) void transpose_f32(const float* __restrict__ src,
                                                     f16* __restrict__ dst, int R, int C) {
  __shared__ float t[32][33];
  size_t zoff = (size_t)blockIdx.z * R * C;
  const float* s = src + zoff;
  int tx = threadIdx.x;
  int ty = threadIdx.y;
  int c0 = blockIdx.x * 32, r0 = blockIdx.y * 32;
#pragma unroll
  for (int i = 0; i < 4; ++i)
    t[ty + i * 8][tx] = s[(size_t)(r0 + ty + i * 8) * C + c0 + tx];
  __syncthreads();
#pragma unroll
  for (int i = 0; i < 4; ++i)
    dst[zoff + (size_t)(c0 + ty + i * 8) * R + r0 + tx] = (f16)t[tx][ty + i * 8];
}

// out[i] = bo[i%D] + sum over nslab split-K partial slabs
__global__ __launch_bounds__(256) void reduce_out(const float* __restrict__ part,
                                                  const float* __restrict__ bo,
                                                  float* __restrict__ out, long n, int nslab) {
  long i = (long)blockIdx.x * 256 + threadIdx.x;
  if (i >= n) return;
  float v = bo[i & (D_ - 1)];
  for (int s = 0; s < nslab; ++s) v += part[(long)s * n + i];
  out[i] = v;
}

struct GemmArgs {
  const f16 *A, *Bm;
  void* C;
  const float* bias;
  float* Mloc;
  int K, lda, ldb, ldc;
  int zbase, NG, PBG;
  long sAp, sAb, sAg, sAz;
  long sBp, sBb, sBg, sBz;
  long sCp, sCb, sCg, sCz;
  long sbp, sbb, sbg, sbz;
  long sMlz;
};

// NT GEMM fp16, fp32 acc — 128x128 2-barrier structure (outproj/fallback).
template <typename OutT, int BIAS, bool PEXP>
__global__ __launch_bounds__(256) void gemm_nt(GemmArgs p) {
  int zloc = blockIdx.z;
  int zi = p.zbase + zloc;
  int pp = zi / p.PBG; int rz = zi - pp * p.PBG;
  int bb = rz / p.NG;  int g = rz - bb * p.NG;
  const f16* A  = p.A + (pp * p.sAp + bb * p.sAb + g * p.sAg + (long)zloc * p.sAz);
  const f16* Bm = p.Bm + (pp * p.sBp + bb * p.sBb + g * p.sBg + (long)zloc * p.sBz);
  OutT* C = (OutT*)p.C + (pp * p.sCp + bb * p.sCb + g * p.sCg + (long)zloc * p.sCz);
  const float* bias = nullptr;
  if (BIAS) bias = p.bias + (pp * p.sbp + bb * p.sbb + g * p.sbg + (long)zloc * p.sbz);

  __shared__ f16 lA[4096];
  __shared__ f16 lB[4096];
  __shared__ float lMx[PEXP ? 256 : 1];

  int tid = threadIdx.x;
  int lane = tid & 63;
  int w = tid >> 6;
  int wm = (w >> 1) << 6;
  int wn = (w & 1) << 6;
  long bm = (long)blockIdx.y * 128;
  long bn = (long)blockIdx.x * 128;

  f32x4 acc[4][4] = {};
  int qd = lane >> 4;
  int fr = lane & 15;

  int q0 = tid, q1 = tid + 256;
  int r0s = q0 >> 2, c0s = (q0 & 3) ^ ((r0s >> 1) & 3);
  int r1s = q1 >> 2, c1s = (q1 & 3) ^ ((r1s >> 1) & 3);

  for (int k0 = 0; k0 < p.K; k0 += 32) {
    long oa0 = (bm + r0s) * (long)p.lda + (k0 + c0s * 8);
    long oa1 = (bm + r1s) * (long)p.lda + (k0 + c1s * 8);
    long ob0 = (bn + r0s) * (long)p.ldb + (k0 + c0s * 8);
    long ob1 = (bn + r1s) * (long)p.ldb + (k0 + c1s * 8);
    __syncthreads();
    async_ld16(A + oa0,  lA + (size_t)q0 * 8);
    async_ld16(A + oa1,  lA + (size_t)q1 * 8);
    async_ld16(Bm + ob0, lB + (size_t)q0 * 8);
    async_ld16(Bm + ob1, lB + (size_t)q1 * 8);
    __syncthreads();

    f16x8 ah[4], bh[4];
#pragma unroll
    for (int i = 0; i < 4; ++i) {
      int m = wm + i * 16 + fr;
      ah[i] = *(const f16x8*)(lA + ((size_t)m * 4 + (qd ^ ((m >> 1) & 3))) * 8);
      int n = wn + i * 16 + fr;
      bh[i] = *(const f16x8*)(lB + ((size_t)n * 4 + (qd ^ ((n >> 1) & 3))) * 8);
    }
#pragma unroll
    for (int i = 0; i < 4; ++i)
#pragma unroll
      for (int j = 0; j < 4; ++j)
        acc[i][j] = __builtin_amdgcn_mfma_f32_16x16x32_f16(ah[i], bh[j], acc[i][j], 0, 0, 0);
  }

  int rr0 = qd * 4;
  if (PEXP) {
#pragma unroll
    for (int i = 0; i < 4; ++i) {
#pragma unroll
      for (int r = 0; r < 4; ++r) {
        float v = fmaxf(fmaxf(acc[i][0][r], acc[i][1][r]),
                        fmaxf(acc[i][2][r], acc[i][3][r]));
        v = fmaxf(v, __shfl_xor(v, 1, 64));
        v = fmaxf(v, __shfl_xor(v, 2, 64));
        v = fmaxf(v, __shfl_xor(v, 4, 64));
        v = fmaxf(v, __shfl_xor(v, 8, 64));
        if (fr == 0) lMx[(w & 1) * 128 + wm + i * 16 + rr0 + r] = v;
      }
    }
    __syncthreads();
    if (tid < 128) {
      float ml = fmaxf(lMx[tid], lMx[128 + tid]);
      p.Mloc[(long)zloc * p.sMlz + (long)blockIdx.x * S_ + bm + tid] = ml;
    }
#pragma unroll
    for (int i = 0; i < 4; ++i) {
#pragma unroll
      for (int r = 0; r < 4; ++r) {
        int rl = wm + i * 16 + rr0 + r;
        float ml = fmaxf(lMx[rl], lMx[128 + rl]);
        long row = bm + rl;
#pragma unroll
        for (int j = 0; j < 4; ++j) {
          long col = bn + wn + j * 16 + fr;
          ((f16*)C)[row * (long)p.ldc + col] = (f16)__expf(acc[i][j][r] - ml);
        }
      }
    }
  } else {
#pragma unroll
    for (int i = 0; i < 4; ++i) {
#pragma unroll
      for (int j = 0; j < 4; ++j) {
#pragma unroll
        for (int r = 0; r < 4; ++r) {
          long row = bm + wm + i * 16 + rr0 + r;
          long col = bn + wn + j * 16 + fr;
          float v = acc[i][j][r];
          if (BIAS == 1) v += bias[col];
          if (BIAS == 2) v += bias[row];
          C[row * (long)p.ldc + col] = (OutT)v;
        }
      }
    }
  }
}

#define QWAIT(N)                                              \
  asm volatile("s_waitcnt vmcnt(" #N ")" ::: "memory");       \
  __builtin_amdgcn_s_barrier();                               \
  __builtin_amdgcn_sched_barrier(0);
#define QBAR()                                                \
  __builtin_amdgcn_s_barrier();                               \
  __builtin_amdgcn_sched_barrier(0);

// ---------------------------------------------------------------------------
// r16: qkv on the 8-phase template with BK=32 -> LDS 64KB -> 2 blocks/CU
// (qkv8-BK64 was latency-bound at 1 block/CU: Occ 18.8%, all pipes ~25-29%).
// Same phase structure as the r9/r11/r15-verified template; loads/half-tile
// 2 -> 1 so vmcnt constants halve (steady 3, tail 2/1/0). WAR re-audited:
// every LDS region >=1 barrier between last reader and next write-issue.
// Buf layout (f16 units): A0@0, A1@4096, B0@8192, B1@12288; buf stride 16384.
// ---------------------------------------------------------------------------
struct QkvArgs {
  const f16 *xh, *wqk, *wv;
  f16 *qk, *vT;
  const float *bqk, *bv;
};

template <int MH, int NH>
__device__ inline void phase_mfma32(const f16* L, int cur, int qr, int qc,
                                    int qd, int fr, f32x4 (&acc)[2][2][4][2]) {
  const f16* Ab = L + cur * 16384 + MH * 4096;
  const f16* Bb = L + cur * 16384 + 8192 + NH * 4096;
  f16x8 af[4], bf[2];
#pragma unroll
  for (int i = 0; i < 4; ++i) {
    int rr = qr * 64 + i * 16 + fr;
    int cc = qd ^ ((rr >> 1) & 3);
    af[i] = *(const f16x8*)(Ab + (size_t)rr * 32 + cc * 8);
  }
#pragma unroll
  for (int j = 0; j < 2; ++j) {
    int rr = qc * 32 + j * 16 + fr;
    int cc = qd ^ ((rr >> 1) & 3);
    bf[j] = *(const f16x8*)(Bb + (size_t)rr * 32 + cc * 8);
  }
  __builtin_amdgcn_s_setprio(1);
#pragma unroll
  for (int i = 0; i < 4; ++i)
#pragma unroll
    for (int j = 0; j < 2; ++j)
      acc[MH][NH][i][j] = __builtin_amdgcn_mfma_f32_16x16x32_f16(
          af[i], bf[j], acc[MH][NH][i][j], 0, 0, 0);
  __builtin_amdgcn_s_setprio(0);
}

__global__ __launch_bounds__(512, 2) void qkv_proj8(QkvArgs p) {
  const long SD = (long)S_ * D_, DD = (long)D_ * D_, DS = (long)D_ * S_;
  int zi = blockIdx.z;
  int pp = zi >> 4;
  int r = zi & 15;
  int b = r >> 3, h = r & 7;
  int bid = blockIdx.x;
  const f16 *A, *Bm;
  f16* C;
  const float* bias;
  long bm, bn;
  int ldc;
  bool biasRow;
  if (pp < 2) {
    A = p.xh + (long)b * SD;
    Bm = p.wqk + ((long)pp * 8 + h) * DD;
    C = p.qk + (long)zi * SD;
    bias = p.bqk + ((long)pp * 8 + h) * D_;
    bm = (long)(bid >> 1) * 256; bn = (long)(bid & 1) * 256;
    ldc = D_; biasRow = false;
  } else {
    A = p.wv + (long)h * DD;
    Bm = p.xh + (long)b * SD;
    C = p.vT + (long)(b * 8 + h) * DS;
    bias = p.bv + (long)h * D_;
    bm = (long)(bid >> 3) * 256; bn = (long)(bid & 7) * 256;
    ldc = S_; biasRow = true;
  }

  __shared__ f16 L[32768];  // 64 KB -> 2 blocks/CU

  int tid = threadIdx.x;
  int lane = tid & 63;
  int w = tid >> 6;
  int qr = w >> 2, qc = w & 3;
  int qd = lane >> 4, fr = lane & 15;

  f32x4 acc[2][2][4][2] = {};

  int srow = tid >> 2;                       // 0..127
  int sslot = (tid & 3) ^ ((srow >> 1) & 3); // swizzled 16B chunk

  // One 8KB half-tile (128 rows x 32 k): 1 gload_lds per thread.
  // Dest linear in tid (wave-uniform base + lane*16B); source pre-swizzled.
  auto stage = [&](const f16* src, long row0, int kb, int ldsBase) {
    async_ld16(src + (row0 + srow) * (long)D_ + (kb + sslot * 8),
               L + ldsBase + (size_t)tid * 8);
  };
  auto iA = [&](int buf, int hh, int t) {
    stage(A, bm + hh * 128, t * 32, buf * 16384 + hh * 4096);
  };
  auto iB = [&](int buf, int hh, int t) {
    stage(Bm, bn + hh * 128, t * 32, buf * 16384 + 8192 + hh * 4096);
  };

  iA(0, 0, 0); iB(0, 0, 0); iB(0, 1, 0); iA(0, 1, 0);

  int cur = 0;
  for (int t = 0; t < 15; ++t) {
    int nxt = cur ^ 1;
    iA(nxt, 0, t + 1);
    QWAIT(3)
    phase_mfma32<0, 0>(L, cur, qr, qc, qd, fr, acc);
    iB(nxt, 0, t + 1);
    QWAIT(3)
    phase_mfma32<0, 1>(L, cur, qr, qc, qd, fr, acc);
    iB(nxt, 1, t + 1);
    QWAIT(3)
    phase_mfma32<1, 0>(L, cur, qr, qc, qd, fr, acc);
    iA(nxt, 1, t + 1);
    QBAR()
    phase_mfma32<1, 1>(L, cur, qr, qc, qd, fr, acc);
    cur = nxt;
  }
  QWAIT(2)
  phase_mfma32<0, 0>(L, cur, qr, qc, qd, fr, acc);
  QWAIT(1)
  phase_mfma32<0, 1>(L, cur, qr, qc, qd, fr, acc);
  QWAIT(0)
  phase_mfma32<1, 0>(L, cur, qr, qc, qd, fr, acc);
  QBAR()
  phase_mfma32<1, 1>(L, cur, qr, qc, qd, fr, acc);

  int rr0 = qd * 4;
#pragma unroll
  for (int mh = 0; mh < 2; ++mh)
#pragma unroll
    for (int nh = 0; nh < 2; ++nh)
#pragma unroll
      for (int i = 0; i < 4; ++i)
#pragma unroll
        for (int j = 0; j < 2; ++j)
#pragma unroll
          for (int rl = 0; rl < 4; ++rl) {
            long row = bm + mh * 128 + qr * 64 + i * 16 + rr0 + rl;
            long col = bn + nh * 128 + qc * 32 + j * 16 + fr;
            float v = acc[mh][nh][i][j][rl] + (biasRow ? bias[row] : bias[col]);
            C[row * (long)ldc + col] = (f16)v;
          }
}

// ---------------------------------------------------------------------------
// BK=64 template pieces (scores8/pv8 — r11/r15-verified, frozen).
// ---------------------------------------------------------------------------
template <int MH, int NH>
__device__ inline void phase_mfma(const f16* L, int cur, int qr, int qc,
                                  int qd, int fr, f32x4 (&acc)[2][2][4][2]) {
  const f16* Ab = L + cur * 32768 + MH * 8192;
  const f16* Bb = L + cur * 32768 + 16384 + NH * 8192;
  f16x8 af[4][2], bf[2][2];
#pragma unroll
  for (int i = 0; i < 4; ++i) {
    int rr = qr * 64 + i * 16 + fr;
#pragma unroll
    for (int ks = 0; ks < 2; ++ks) {
      int cc = ks * 4 + qd;
      af[i][ks] = *(const f16x8*)(Ab + ((size_t)rr * 8 + (cc ^ ((rr >> 1) & 7))) * 8);
    }
  }
#pragma unroll
  for (int j = 0; j < 2; ++j) {
    int rr = qc * 32 + j * 16 + fr;
#pragma unroll
    for (int ks = 0; ks < 2; ++ks) {
      int cc = ks * 4 + qd;
      bf[j][ks] = *(const f16x8*)(Bb + ((size_t)rr * 8 + (cc ^ ((rr >> 1) & 7))) * 8);
    }
  }
  __builtin_amdgcn_s_setprio(1);
#pragma unroll
  for (int i = 0; i < 4; ++i)
#pragma unroll
    for (int j = 0; j < 2; ++j)
#pragma unroll
      for (int ks = 0; ks < 2; ++ks)
        acc[MH][NH][i][j] = __builtin_amdgcn_mfma_f32_16x16x32_f16(
            af[i][ks], bf[j][ks], acc[MH][NH][i][j], 0, 0, 0);
  __builtin_amdgcn_s_setprio(0);
}

struct Sc8Args {
  const f16 *Q, *K;
  f16* P;
  float* Ml;
};

__global__ __launch_bounds__(512, 2) void scores8(Sc8Args p) {
  int zloc = blockIdx.z;
  const f16* A  = p.Q + (long)zloc * S_ * D_;
  const f16* Bm = p.K + (long)zloc * S_ * D_;
  f16* C = p.P + (long)zloc * (long)S_ * S_;
  float* Ml = p.Ml + (long)zloc * 16L * S_;
  int bid = blockIdx.x;
  long bm = (long)(bid >> 3) * 256, bn = (long)(bid & 7) * 256;

  __shared__ f16 L[65536];        // 128 KB
  __shared__ float lMx2[4][256];  // 4 KB per-wave-col row maxes

  int tid = threadIdx.x;
  int lane = tid & 63;
  int w = tid >> 6;
  int qr = w >> 2, qc = w & 3;
  int qd = lane >> 4, fr = lane & 15;

  f32x4 acc[2][2][4][2] = {};

  int srl = w * 16 + (lane >> 3);
  int sslot = lane & 7;

  auto stage = [&](const f16* src, long row0, int kb, int ldsBase) {
#pragma unroll
    for (int k = 0; k < 2; ++k) {
      int rl = srl + k * 8;
      int c = sslot ^ ((rl >> 1) & 7);
      async_ld16(src + (row0 + rl) * (long)D_ + (kb + c * 8),
                 L + ldsBase + (w * 2 + k) * 512 + lane * 8);
    }
  };
  auto iA = [&](int buf, int hh, int t) {
    stage(A, bm + hh * 128, t * 64, buf * 32768 + hh * 8192);
  };
  auto iB = [&](int buf, int hh, int t) {
    stage(Bm, bn + hh * 128, t * 64, buf * 32768 + 16384 + hh * 8192);
  };

  iA(0, 0, 0); iB(0, 0, 0); iB(0, 1, 0); iA(0, 1, 0);

  int cur = 0;
  for (int t = 0; t < 7; ++t) {
    int nxt = cur ^ 1;
    iA(nxt, 0, t + 1);
    QWAIT(6)
    phase_mfma<0, 0>(L, cur, qr, qc, qd, fr, acc);
    iB(nxt, 0, t + 1);
    QWAIT(6)
    phase_mfma<0, 1>(L, cur, qr, qc, qd, fr, acc);
    iB(nxt, 1, t + 1);
    QWAIT(6)
    phase_mfma<1, 0>(L, cur, qr, qc, qd, fr, acc);
    iA(nxt, 1, t + 1);
    QBAR()
    phase_mfma<1, 1>(L, cur, qr, qc, qd, fr, acc);
    cur = nxt;
  }
  QWAIT(4)
  phase_mfma<0, 0>(L, cur, qr, qc, qd, fr, acc);
  QWAIT(2)
  phase_mfma<0, 1>(L, cur, qr, qc, qd, fr, acc);
  QWAIT(0)
  phase_mfma<1, 0>(L, cur, qr, qc, qd, fr, acc);
  QBAR()
  phase_mfma<1, 1>(L, cur, qr, qc, qd, fr, acc);

  // --- PEXP epilogue ---
#pragma unroll
  for (int mh = 0; mh < 2; ++mh)
#pragma unroll
    for (int i = 0; i < 4; ++i)
#pragma unroll
      for (int rl = 0; rl < 4; ++rl) {
        float v = fmaxf(fmaxf(acc[mh][0][i][0][rl], acc[mh][0][i][1][rl]),
                        fmaxf(acc[mh][1][i][0][rl], acc[mh][1][i][1][rl]));
        v = fmaxf(v, __shfl_xor(v, 1, 64));
        v = fmaxf(v, __shfl_xor(v, 2, 64));
        v = fmaxf(v, __shfl_xor(v, 4, 64));
        v = fmaxf(v, __shfl_xor(v, 8, 64));
        if (fr == 0) lMx2[qc][mh * 128 + qr * 64 + i * 16 + qd * 4 + rl] = v;
      }
  __syncthreads();
  if (tid < 256) {
    float ml = fmaxf(fmaxf(lMx2[0][tid], lMx2[1][tid]),
                     fmaxf(lMx2[2][tid], lMx2[3][tid]));
    int cb0 = (bid & 7) * 2;
    Ml[(long)cb0 * S_ + bm + tid] = ml;
    Ml[(long)(cb0 + 1) * S_ + bm + tid] = ml;
  }
#pragma unroll
  for (int mh = 0; mh < 2; ++mh)
#pragma unroll
    for (int i = 0; i < 4; ++i)
#pragma unroll
      for (int rl = 0; rl < 4; ++rl) {
        int rowLoc = mh * 128 + qr * 64 + i * 16 + qd * 4 + rl;
        float ml = fmaxf(fmaxf(lMx2[0][rowLoc], lMx2[1][rowLoc]),
                         fmaxf(lMx2[2][rowLoc], lMx2[3][rowLoc]));
        long row = bm + rowLoc;
#pragma unroll
        for (int nh = 0; nh < 2; ++nh)
#pragma unroll
          for (int j = 0; j < 2; ++j) {
            long col = bn + nh * 128 + qc * 32 + j * 16 + fr;
            C[row * (long)S_ + col] = (f16)__expf(acc[mh][nh][i][j][rl] - ml);
          }
      }
}

// ---------------------------------------------------------------------------
// flash-PV on the 8-phase template (r15-verified, frozen).
// ---------------------------------------------------------------------------
struct PvArgs {
  const f16* S; const float* Ml; const f16* V; f16* C;
  int ldc, zbase, NG;
  long sVz, sCb, sCg;
};

template <int MH>
__device__ inline void pv_phase(const f16* L, int cur, int qr, int qc, int qd,
                                int fr, const f16 (&al)[2][4],
                                f32x4 (&acc)[2][4][2], f32x4 (&lacc)[2][4],
                                f16x8 ones) {
  const f16* Ab = L + cur * 24576 + MH * 8192;
  const f16* Bb = L + cur * 24576 + 16384;
  f16x8 af[4][2], bf[2][2];
#pragma unroll
  for (int i = 0; i < 4; ++i) {
    int rr = qr * 64 + i * 16 + fr;
#pragma unroll
    for (int ks = 0; ks < 2; ++ks) {
      int cc = ks * 4 + qd;
      af[i][ks] = *(const f16x8*)(Ab + ((size_t)rr * 8 + (cc ^ ((rr >> 1) & 7))) * 8);
#pragma unroll
      for (int e = 0; e < 8; ++e) af[i][ks][e] *= al[MH][i];
    }
  }
#pragma unroll
  for (int j = 0; j < 2; ++j) {
    int rr = qc * 32 + j * 16 + fr;
#pragma unroll
    for (int ks = 0; ks < 2; ++ks) {
      int cc = ks * 4 + qd;
      bf[j][ks] = *(const f16x8*)(Bb + ((size_t)rr * 8 + (cc ^ ((rr >> 1) & 7))) * 8);
    }
  }
  __builtin_amdgcn_s_setprio(1);
#pragma unroll
  for (int i = 0; i < 4; ++i) {
    f16x8 a2 = af[i][0] + af[i][1];
    lacc[MH][i] = __builtin_amdgcn_mfma_f32_16x16x32_f16(a2, ones, lacc[MH][i], 0, 0, 0);
#pragma unroll
    for (int j = 0; j < 2; ++j)
#pragma unroll
      for (int ks = 0; ks < 2; ++ks)
        acc[MH][i][j] = __builtin_amdgcn_mfma_f32_16x16x32_f16(
            af[i][ks], bf[j][ks], acc[MH][i][j], 0, 0, 0);
  }
  __builtin_amdgcn_s_setprio(0);
}

__global__ __launch_bounds__(512, 2) void pv_flash8(PvArgs p) {
  int zloc = blockIdx.z;
  int zi = p.zbase + zloc;
  int bb = zi / p.NG; int g = zi - bb * p.NG;
  const f16* Sm = p.S + (long)zloc * S_ * S_;
  const float* MlG = p.Ml + (long)zloc * 16 * S_;
  const f16* V = p.V + (long)zloc * p.sVz;
  f16* C = p.C + bb * p.sCb + g * p.sCg;

  __shared__ f16 L[49152];     // 96 KB: 2 bufs x (A0,A1,B of 8K f16 each)
  __shared__ float lMl[4096];  // 16 KB: [cb][256 rows]

  int tid = threadIdx.x;
  int lane = tid & 63;
  int w = tid >> 6;
  int qr = w >> 2, qc = w & 3;
  int qd = lane >> 4, fr = lane & 15;

  int bid = blockIdx.x;
  long bm = (long)(bid >> 2) * 256;
  long bn = (long)(bid & 3) * 128;

  f32x4 acc[2][4][2] = {};
  f32x4 lacc[2][4] = {};
  f16x8 ones;
#pragma unroll
  for (int e = 0; e < 8; ++e) ones[e] = (f16)1.0f;

  int srl = w * 16 + (lane >> 3);
  int sslot = lane & 7;

  auto stage = [&](const f16* src, long row0, int kb, int ldsBase) {
#pragma unroll
    for (int k = 0; k < 2; ++k) {
      int rl = srl + k * 8;
      int c = sslot ^ ((rl >> 1) & 7);
      async_ld16(src + (row0 + rl) * (long)S_ + (kb + c * 8),
                 L + ldsBase + (w * 2 + k) * 512 + lane * 8);
    }
  };
  auto iA = [&](int buf, int hh, int t) {
    stage(Sm, bm + hh * 128, t * 64, buf * 24576 + hh * 8192);
  };
  auto iB = [&](int buf, int t) {
    stage(V, bn, t * 64, buf * 24576 + 16384);
  };

  // Prologue: stage Ml slab [16 cb][bm..bm+255] into LDS.
  // dest = wave-uniform base (cb*1024B) + lane*16B; row cb = k*8 + w.
#pragma unroll
  for (int k = 0; k < 2; ++k) {
    int cb = k * 8 + w;
    async_ld16(MlG + (long)cb * S_ + bm + lane * 4,
               (char*)lMl + (size_t)cb * 1024 + (size_t)lane * 16);
  }
  iA(0, 0, 0); iB(0, 0); iA(0, 1, 0);
  asm volatile("s_waitcnt vmcnt(6)" ::: "memory");
  __builtin_amdgcn_s_barrier();

  // mg over 16 cb from LDS; al for cb=0.
  float mg[2][4];
  f16 al[2][4];
#pragma unroll
  for (int mh = 0; mh < 2; ++mh)
#pragma unroll
    for (int i = 0; i < 4; ++i) {
      int rloc = mh * 128 + qr * 64 + i * 16 + fr;
      float m = -1e30f;
#pragma unroll
      for (int cb = 0; cb < 16; ++cb)
        m = fmaxf(m, lMl[cb * 256 + rloc]);
      mg[mh][i] = m;
      al[mh][i] = (f16)__expf(lMl[rloc] - m);
    }

  int cur = 0;
  for (int t = 0; t < 31; ++t) {
    int nxt = cur ^ 1;
    if (t && (t & 1) == 0) {
      int cb = t >> 1;
#pragma unroll
      for (int mh = 0; mh < 2; ++mh)
#pragma unroll
        for (int i = 0; i < 4; ++i) {
          int rloc = mh * 128 + qr * 64 + i * 16 + fr;
          al[mh][i] = (f16)__expf(lMl[cb * 256 + rloc] - mg[mh][i]);
        }
    }
    iA(nxt, 0, t + 1);
    QWAIT(4)                     // drains A0(t)+B(t)
    pv_phase<0>(L, cur, qr, qc, qd, fr, al, acc, lacc, ones);
    iB(nxt, t + 1);
    iA(nxt, 1, t + 1);           // B/A1 writes behind ph<0>'s barrier
    QWAIT(6)                     // drains A1(t)
    pv_phase<1>(L, cur, qr, qc, qd, fr, al, acc, lacc, ones);
    cur = nxt;
  }
  {  // t = 31 tail
    int cb = 15;
#pragma unroll
    for (int mh = 0; mh < 2; ++mh)
#pragma unroll
      for (int i = 0; i < 4; ++i) {
        int rloc = mh * 128 + qr * 64 + i * 16 + fr;
        al[mh][i] = (f16)__expf(lMl[cb * 256 + rloc] - mg[mh][i]);
      }
  }
  QWAIT(2)
  pv_phase<0>(L, cur, qr, qc, qd, fr, al, acc, lacc, ones);
  QWAIT(0)
  pv_phase<1>(L, cur, qr, qc, qd, fr, al, acc, lacc, ones);

  int rr0 = qd * 4;
#pragma unroll
  for (int mh = 0; mh < 2; ++mh)
#pragma unroll
    for (int i = 0; i < 4; ++i) {
      float inv[4];
#pragma unroll
      for (int rl = 0; rl < 4; ++rl) inv[rl] = 1.0f / lacc[mh][i][rl];
#pragma unroll
      for (int j = 0; j < 2; ++j)
#pragma unroll
        for (int rl = 0; rl < 4; ++rl) {
          long row = bm + mh * 128 + qr * 64 + i * 16 + rr0 + rl;
          long col = bn + qc * 32 + j * 16 + fr;
          C[row * (long)p.ldc + col] = (f16)(acc[mh][i][j][rl] * inv[rl]);
        }
    }
}

extern "C" void kernel_launch(void* const* d_in, const int* in_sizes, int n_in,
                              void* d_out, int out_size, void* d_ws, size_t ws_size,
                              hipStream_t stream) {
  const float* x  = (const float*)d_in[0];
  const float* Wq = (const float*)d_in[1];
  const float* bq = (const float*)d_in[2];
  const float* Wk = (const float*)d_in[3];
  const float* bk = (const float*)d_in[4];
  const float* Wv = (const float*)d_in[5];
  const float* bv = (const float*)d_in[6];
  const float* Wo = (const float*)d_in[7];
  const float* bo = (const float*)d_in[8];
  float* out = (float*)d_out;

  auto al = [](size_t v) { return (v + 255) & ~(size_t)255; };
  const size_t eX = (size_t)B_ * S_ * D_;
  const size_t eW = (size_t)H_ * D_ * D_;
  const size_t eSS = (size_t)S_ * S_;
  const long SD = (long)S_ * D_;
  const long DD = (long)D_ * D_;
  const long DS = (long)D_ * S_;

  size_t fixed = al(eX * 2) + al(2 * eW * 2) + al(eW * 2) + al(eW * 2)
               + al(2ULL * H_ * D_ * 4);
  int NB = 1, GH = 1, GS = 1; bool found = false;
  for (int nb = 2; nb >= 1 && !found; --nb)
    for (int gh = 8; gh >= 1 && !found; gh >>= 1)
      for (int gs = nb * gh; gs >= 1 && !found; gs >>= 1) {
        size_t need = fixed + al((size_t)nb * S_ * H_ * D_ * 2)
                    + al(2ULL * nb * gh * S_ * D_ * 2)
                    + al((size_t)nb * gh * D_ * S_ * 2)
                    + al(4ULL * nb * SD * 4)
                    + al((size_t)gs * eSS * 2)
                    + al((size_t)gs * 16 * S_ * 4);
        if (need <= ws_size) { NB = nb; GH = gh; GS = gs; found = true; }
      }

  char* p0 = (char*)d_ws;
  size_t off = 0;
  f16* xh    = (f16*)(p0 + off); off += al(eX * 2);
  f16* wqk   = (f16*)(p0 + off); off += al(2 * eW * 2);
  f16* wv    = (f16*)(p0 + off); off += al(eW * 2);
  f16* wo    = (f16*)(p0 + off); off += al(eW * 2);
  float* bqk = (float*)(p0 + off); off += al(2ULL * H_ * D_ * 4);
  f16* catb  = (f16*)(p0 + off); off += al((size_t)NB * S_ * H_ * D_ * 2);
  f16* qk    = (f16*)(p0 + off); off += al(2ULL * NB * GH * S_ * D_ * 2);
  f16* vT    = (f16*)(p0 + off); off += al((size_t)NB * GH * D_ * S_ * 2);
  float* opart = (float*)(p0 + off); off += al(4ULL * NB * SD * 4);
  f16* scores = (f16*)(p0 + off); off += al((size_t)GS * eSS * 2);
  float* mloc = (float*)(p0 + off);

  // ---- prep ----
  cvt_f16<<<dim3((unsigned)((eX + 255) / 256)), 256, 0, stream>>>(x, xh, (long)eX);
  dim3 tb(32, 8, 1);
  transpose_f32<<<dim3(16, 16, H_), tb, 0, stream>>>(Wq, wqk, D_, D_);
  transpose_f32<<<dim3(16, 16, H_), tb, 0, stream>>>(Wk, wqk + eW, D_, D_);
  transpose_f32<<<dim3(16, 16, H_), tb, 0, stream>>>(Wv, wv, D_, D_);
  transpose_f32<<<dim3(16, 128, 1), tb, 0, stream>>>(Wo, wo, H_ * D_, D_);
  hipMemcpyAsync(bqk, bq, (size_t)H_ * D_ * 4, hipMemcpyDeviceToDevice, stream);
  hipMemcpyAsync(bqk + H_ * D_, bk, (size_t)H_ * D_ * 4, hipMemcpyDeviceToDevice, stream);

  for (int b0 = 0; b0 < B_; b0 += NB) {
    for (int h0 = 0; h0 < H_; h0 += GH) {
      if (NB == 2 && GH == 8) {
        QkvArgs a{xh, wqk, wv, qk, vT, bqk, bv};
        qkv_proj8<<<dim3(16, 1, 48), 512, 0, stream>>>(a);
      } else {
        {  // Q+K projections
          GemmArgs a{};
          a.A = xh + (long)b0 * SD;
          a.Bm = wqk + (long)h0 * DD;
          a.C = qk; a.bias = bqk + (long)h0 * D_;
          a.K = D_; a.lda = D_; a.ldb = D_; a.ldc = D_;
          a.zbase = 0; a.NG = GH; a.PBG = NB * GH;
          a.sAb = SD;
          a.sBp = (long)H_ * DD; a.sBg = DD;
          a.sCz = SD;
          a.sbp = (long)H_ * D_; a.sbg = D_;
          gemm_nt<f16, 1, false><<<dim3(4, 16, 2 * NB * GH), 256, 0, stream>>>(a);
        }
        {  // V^T
          GemmArgs a{};
          a.A = wv + (long)h0 * DD; a.Bm = xh + (long)b0 * SD;
          a.C = vT; a.bias = bv + (long)h0 * D_;
          a.K = D_; a.lda = D_; a.ldb = D_; a.ldc = S_;
          a.zbase = 0; a.NG = GH; a.PBG = NB * GH;
          a.sAg = DD;
          a.sBb = SD;
          a.sCz = DS;
          a.sbg = D_;
          gemm_nt<f16, 2, false><<<dim3(16, 4, NB * GH), 256, 0, stream>>>(a);
        }
      }
      for (int g0 = 0; g0 < NB * GH; g0 += GS) {
        {  // scores -> P = exp(s - ml256) f16, Mloc (8-phase template)
          Sc8Args a{qk + (long)g0 * SD, qk + ((long)NB * GH + g0) * SD,
                    scores, mloc};
          scores8<<<dim3(64, 1, GS), 512, 0, stream>>>(a);
        }
        {  // flash PV on the 8-phase template (256x128, 32-tile pipeline)
          PvArgs a{};
          a.S = scores; a.Ml = mloc; a.V = vT + (long)g0 * DS;
          a.C = catb + (long)h0 * D_;
          a.ldc = H_ * D_; a.zbase = g0; a.NG = GH;
          a.sVz = DS; a.sCb = (long)S_ * H_ * D_; a.sCg = D_;
          pv_flash8<<<dim3(32, 1, GS), 512, 0, stream>>>(a);
        }
      }
    }
    {  // out-proj split-K (4 slabs of 1024)
      GemmArgs a{};
      a.A = catb; a.Bm = wo;
      a.C = opart;
      a.K = 1024; a.lda = H_ * D_; a.ldb = H_ * D_; a.ldc = D_;
      a.zbase = 0; a.NG = 4; a.PBG = NB * 4;
      a.sAb = (long)S_ * H_ * D_; a.sAg = 1024;
      a.sBg = 1024;
      a.sCb = SD; a.sCg = (long)NB * SD;
      gemm_nt<float, 0, false><<<dim3(4, 16, NB * 4), 256, 0, stream>>>(a);
    }
    reduce_out<<<dim3((unsigned)(((long)NB * SD + 255) / 256)), 256, 0, stream>>>(
        opart, bo, out + (long)b0 * SD, (long)NB * SD, 4);
  }
}

// Round 17
// 446.613 us; speedup vs baseline: 1.0938x; 1.0110x over previous
//
#include <hip/hip_runtime.h>

typedef _Float16 f16;
typedef _Float16 f16x8 __attribute__((ext_vector_type(8)));
typedef float f32x4 __attribute__((ext_vector_type(4)));

#define B_ 2
#define S_ 2048
#define D_ 512
#define H_ 8

__device__ inline void async_ld16(const void* g, void* l) {
  __builtin_amdgcn_global_load_lds((__attribute__((address_space(1))) void*)(g),
                                   (__attribute__((address_space(3))) void*)(l),
                                   16, 0, 0);
}

__global__ __launch_bounds__(256) void cvt_f16(const float* __restrict__ src,
                                               f16* __restrict__ dst, long n) {
  long i = (long)blockIdx.x * 256 + threadIdx.x;
  if (i >= n) return;
  dst[i] = (f16)src[i];
}

// [z][R][C] fp32 -> [z][C][R] fp16
__global__ __launch_bounds__(256) void transpose_f32(const float* __restrict__ src,
                                                     f16* __restrict__ dst, int R, int C) {
  __shared__ float t[32][33];
  size_t zoff = (size_t)blockIdx.z * R * C;
  const float* s = src + zoff;
  int tx = threadIdx.x;
  int ty = threadIdx.y;
  int c0 = blockIdx.x * 32, r0 = blockIdx.y * 32;
#pragma unroll
  for (int i = 0; i < 4; ++i)
    t[ty + i * 8][tx] = s[(size_t)(r0 + ty + i * 8) * C + c0 + tx];
  __syncthreads();
#pragma unroll
  for (int i = 0; i < 4; ++i)
    dst[zoff + (size_t)(c0 + ty + i * 8) * R + r0 + tx] = (f16)t[tx][ty + i * 8];
}

// out[i] = bo[i%D] + sum over nslab split-K partial slabs
__global__ __launch_bounds__(256) void reduce_out(const float* __restrict__ part,
                                                  const float* __restrict__ bo,
                                                  float* __restrict__ out, long n, int nslab) {
  long i = (long)blockIdx.x * 256 + threadIdx.x;
  if (i >= n) return;
  float v = bo[i & (D_ - 1)];
  for (int s = 0; s < nslab; ++s) v += part[(long)s * n + i];
  out[i] = v;
}

struct GemmArgs {
  const f16 *A, *Bm;
  void* C;
  const float* bias;
  float* Mloc;
  int K, lda, ldb, ldc;
  int zbase, NG, PBG;
  long sAp, sAb, sAg, sAz;
  long sBp, sBb, sBg, sBz;
  long sCp, sCb, sCg, sCz;
  long sbp, sbb, sbg, sbz;
  long sMlz;
};

// NT GEMM fp16, fp32 acc — 128x128 2-barrier structure (outproj/fallback).
template <typename OutT, int BIAS, bool PEXP>
__global__ __launch_bounds__(256) void gemm_nt(GemmArgs p) {
  int zloc = blockIdx.z;
  int zi = p.zbase + zloc;
  int pp = zi / p.PBG; int rz = zi - pp * p.PBG;
  int bb = rz / p.NG;  int g = rz - bb * p.NG;
  const f16* A  = p.A + (pp * p.sAp + bb * p.sAb + g * p.sAg + (long)zloc * p.sAz);
  const f16* Bm = p.Bm + (pp * p.sBp + bb * p.sBb + g * p.sBg + (long)zloc * p.sBz);
  OutT* C = (OutT*)p.C + (pp * p.sCp + bb * p.sCb + g * p.sCg + (long)zloc * p.sCz);
  const float* bias = nullptr;
  if (BIAS) bias = p.bias + (pp * p.sbp + bb * p.sbb + g * p.sbg + (long)zloc * p.sbz);

  __shared__ f16 lA[4096];
  __shared__ f16 lB[4096];
  __shared__ float lMx[PEXP ? 256 : 1];

  int tid = threadIdx.x;
  int lane = tid & 63;
  int w = tid >> 6;
  int wm = (w >> 1) << 6;
  int wn = (w & 1) << 6;
  long bm = (long)blockIdx.y * 128;
  long bn = (long)blockIdx.x * 128;

  f32x4 acc[4][4] = {};
  int qd = lane >> 4;
  int fr = lane & 15;

  int q0 = tid, q1 = tid + 256;
  int r0s = q0 >> 2, c0s = (q0 & 3) ^ ((r0s >> 1) & 3);
  int r1s = q1 >> 2, c1s = (q1 & 3) ^ ((r1s >> 1) & 3);

  for (int k0 = 0; k0 < p.K; k0 += 32) {
    long oa0 = (bm + r0s) * (long)p.lda + (k0 + c0s * 8);
    long oa1 = (bm + r1s) * (long)p.lda + (k0 + c1s * 8);
    long ob0 = (bn + r0s) * (long)p.ldb + (k0 + c0s * 8);
    long ob1 = (bn + r1s) * (long)p.ldb + (k0 + c1s * 8);
    __syncthreads();
    async_ld16(A + oa0,  lA + (size_t)q0 * 8);
    async_ld16(A + oa1,  lA + (size_t)q1 * 8);
    async_ld16(Bm + ob0, lB + (size_t)q0 * 8);
    async_ld16(Bm + ob1, lB + (size_t)q1 * 8);
    __syncthreads();

    f16x8 ah[4], bh[4];
#pragma unroll
    for (int i = 0; i < 4; ++i) {
      int m = wm + i * 16 + fr;
      ah[i] = *(const f16x8*)(lA + ((size_t)m * 4 + (qd ^ ((m >> 1) & 3))) * 8);
      int n = wn + i * 16 + fr;
      bh[i] = *(const f16x8*)(lB + ((size_t)n * 4 + (qd ^ ((n >> 1) & 3))) * 8);
    }
#pragma unroll
    for (int i = 0; i < 4; ++i)
#pragma unroll
      for (int j = 0; j < 4; ++j)
        acc[i][j] = __builtin_amdgcn_mfma_f32_16x16x32_f16(ah[i], bh[j], acc[i][j], 0, 0, 0);
  }

  int rr0 = qd * 4;
  if (PEXP) {
#pragma unroll
    for (int i = 0; i < 4; ++i) {
#pragma unroll
      for (int r = 0; r < 4; ++r) {
        float v = fmaxf(fmaxf(acc[i][0][r], acc[i][1][r]),
                        fmaxf(acc[i][2][r], acc[i][3][r]));
        v = fmaxf(v, __shfl_xor(v, 1, 64));
        v = fmaxf(v, __shfl_xor(v, 2, 64));
        v = fmaxf(v, __shfl_xor(v, 4, 64));
        v = fmaxf(v, __shfl_xor(v, 8, 64));
        if (fr == 0) lMx[(w & 1) * 128 + wm + i * 16 + rr0 + r] = v;
      }
    }
    __syncthreads();
    if (tid < 128) {
      float ml = fmaxf(lMx[tid], lMx[128 + tid]);
      p.Mloc[(long)zloc * p.sMlz + (long)blockIdx.x * S_ + bm + tid] = ml;
    }
#pragma unroll
    for (int i = 0; i < 4; ++i) {
#pragma unroll
      for (int r = 0; r < 4; ++r) {
        int rl = wm + i * 16 + rr0 + r;
        float ml = fmaxf(lMx[rl], lMx[128 + rl]);
        long row = bm + rl;
#pragma unroll
        for (int j = 0; j < 4; ++j) {
          long col = bn + wn + j * 16 + fr;
          ((f16*)C)[row * (long)p.ldc + col] = (f16)__expf(acc[i][j][r] - ml);
        }
      }
    }
  } else {
#pragma unroll
    for (int i = 0; i < 4; ++i) {
#pragma unroll
      for (int j = 0; j < 4; ++j) {
#pragma unroll
        for (int r = 0; r < 4; ++r) {
          long row = bm + wm + i * 16 + rr0 + r;
          long col = bn + wn + j * 16 + fr;
          float v = acc[i][j][r];
          if (BIAS == 1) v += bias[col];
          if (BIAS == 2) v += bias[row];
          C[row * (long)p.ldc + col] = (OutT)v;
        }
      }
    }
  }
}

// ---------------------------------------------------------------------------
// 256x256 8-phase counted-vmcnt template (T3+T4+T5) — r9/r11/r15-verified.
// BK=64 (r16: BK=32 regressed qkv 71.5->78.3, occupancy did NOT rise).
// ---------------------------------------------------------------------------
struct QkvArgs {
  const f16 *xh, *wqk, *wv;
  f16 *qk, *vT;
  const float *bqk, *bv;
};

template <int MH, int NH>
__device__ inline void phase_mfma(const f16* L, int cur, int qr, int qc,
                                  int qd, int fr, f32x4 (&acc)[2][2][4][2]) {
  const f16* Ab = L + cur * 32768 + MH * 8192;
  const f16* Bb = L + cur * 32768 + 16384 + NH * 8192;
  f16x8 af[4][2], bf[2][2];
#pragma unroll
  for (int i = 0; i < 4; ++i) {
    int rr = qr * 64 + i * 16 + fr;
#pragma unroll
    for (int ks = 0; ks < 2; ++ks) {
      int cc = ks * 4 + qd;
      af[i][ks] = *(const f16x8*)(Ab + ((size_t)rr * 8 + (cc ^ ((rr >> 1) & 7))) * 8);
    }
  }
#pragma unroll
  for (int j = 0; j < 2; ++j) {
    int rr = qc * 32 + j * 16 + fr;
#pragma unroll
    for (int ks = 0; ks < 2; ++ks) {
      int cc = ks * 4 + qd;
      bf[j][ks] = *(const f16x8*)(Bb + ((size_t)rr * 8 + (cc ^ ((rr >> 1) & 7))) * 8);
    }
  }
  __builtin_amdgcn_s_setprio(1);
#pragma unroll
  for (int i = 0; i < 4; ++i)
#pragma unroll
    for (int j = 0; j < 2; ++j)
#pragma unroll
      for (int ks = 0; ks < 2; ++ks)
        acc[MH][NH][i][j] = __builtin_amdgcn_mfma_f32_16x16x32_f16(
            af[i][ks], bf[j][ks], acc[MH][NH][i][j], 0, 0, 0);
  __builtin_amdgcn_s_setprio(0);
}

#define QWAIT(N)                                              \
  asm volatile("s_waitcnt vmcnt(" #N ")" ::: "memory");       \
  __builtin_amdgcn_s_barrier();                               \
  __builtin_amdgcn_sched_barrier(0);
#define QBAR()                                                \
  __builtin_amdgcn_s_barrier();                               \
  __builtin_amdgcn_sched_barrier(0);

__global__ __launch_bounds__(512, 2) void qkv_proj8(QkvArgs p) {
  const long SD = (long)S_ * D_, DD = (long)D_ * D_, DS = (long)D_ * S_;
  int zi = blockIdx.z;
  int pp = zi >> 4;
  int r = zi & 15;
  int b = r >> 3, h = r & 7;
  int bid = blockIdx.x;
  const f16 *A, *Bm;
  f16* C;
  const float* bias;
  long bm, bn;
  int ldc;
  bool biasRow;
  if (pp < 2) {
    A = p.xh + (long)b * SD;
    Bm = p.wqk + ((long)pp * 8 + h) * DD;
    C = p.qk + (long)zi * SD;
    bias = p.bqk + ((long)pp * 8 + h) * D_;
    bm = (long)(bid >> 1) * 256; bn = (long)(bid & 1) * 256;
    ldc = D_; biasRow = false;
  } else {
    A = p.wv + (long)h * DD;
    Bm = p.xh + (long)b * SD;
    C = p.vT + (long)(b * 8 + h) * DS;
    bias = p.bv + (long)h * D_;
    bm = (long)(bid >> 3) * 256; bn = (long)(bid & 7) * 256;
    ldc = S_; biasRow = true;
  }

  __shared__ f16 L[65536];  // 128 KB

  int tid = threadIdx.x;
  int lane = tid & 63;
  int w = tid >> 6;
  int qr = w >> 2, qc = w & 3;
  int qd = lane >> 4, fr = lane & 15;

  f32x4 acc[2][2][4][2] = {};

  int srl = w * 16 + (lane >> 3);
  int sslot = lane & 7;

  auto stage = [&](const f16* src, long row0, int kb, int ldsBase) {
#pragma unroll
    for (int k = 0; k < 2; ++k) {
      int rl = srl + k * 8;
      int c = sslot ^ ((rl >> 1) & 7);
      async_ld16(src + (row0 + rl) * (long)D_ + (kb + c * 8),
                 L + ldsBase + (w * 2 + k) * 512 + lane * 8);
    }
  };
  auto iA = [&](int buf, int hh, int t) {
    stage(A, bm + hh * 128, t * 64, buf * 32768 + hh * 8192);
  };
  auto iB = [&](int buf, int hh, int t) {
    stage(Bm, bn + hh * 128, t * 64, buf * 32768 + 16384 + hh * 8192);
  };

  iA(0, 0, 0); iB(0, 0, 0); iB(0, 1, 0); iA(0, 1, 0);

  int cur = 0;
  for (int t = 0; t < 7; ++t) {
    int nxt = cur ^ 1;
    iA(nxt, 0, t + 1);
    QWAIT(6)
    phase_mfma<0, 0>(L, cur, qr, qc, qd, fr, acc);
    iB(nxt, 0, t + 1);
    QWAIT(6)
    phase_mfma<0, 1>(L, cur, qr, qc, qd, fr, acc);
    iB(nxt, 1, t + 1);
    QWAIT(6)
    phase_mfma<1, 0>(L, cur, qr, qc, qd, fr, acc);
    iA(nxt, 1, t + 1);
    QBAR()
    phase_mfma<1, 1>(L, cur, qr, qc, qd, fr, acc);
    cur = nxt;
  }
  QWAIT(4)
  phase_mfma<0, 0>(L, cur, qr, qc, qd, fr, acc);
  QWAIT(2)
  phase_mfma<0, 1>(L, cur, qr, qc, qd, fr, acc);
  QWAIT(0)
  phase_mfma<1, 0>(L, cur, qr, qc, qd, fr, acc);
  QBAR()
  phase_mfma<1, 1>(L, cur, qr, qc, qd, fr, acc);

  int rr0 = qd * 4;
#pragma unroll
  for (int mh = 0; mh < 2; ++mh)
#pragma unroll
    for (int nh = 0; nh < 2; ++nh)
#pragma unroll
      for (int i = 0; i < 4; ++i)
#pragma unroll
        for (int j = 0; j < 2; ++j)
#pragma unroll
          for (int rl = 0; rl < 4; ++rl) {
            long row = bm + mh * 128 + qr * 64 + i * 16 + rr0 + rl;
            long col = bn + nh * 128 + qc * 32 + j * 16 + fr;
            float v = acc[mh][nh][i][j][rl] + (biasRow ? bias[row] : bias[col]);
            C[row * (long)ldc + col] = (f16)v;
          }
}

// ---------------------------------------------------------------------------
// scores on the 8-phase template (r11-verified, frozen).
// ---------------------------------------------------------------------------
struct Sc8Args {
  const f16 *Q, *K;
  f16* P;
  float* Ml;
};

__global__ __launch_bounds__(512, 2) void scores8(Sc8Args p) {
  int zloc = blockIdx.z;
  const f16* A  = p.Q + (long)zloc * S_ * D_;
  const f16* Bm = p.K + (long)zloc * S_ * D_;
  f16* C = p.P + (long)zloc * (long)S_ * S_;
  float* Ml = p.Ml + (long)zloc * 16L * S_;
  int bid = blockIdx.x;
  long bm = (long)(bid >> 3) * 256, bn = (long)(bid & 7) * 256;

  __shared__ f16 L[65536];        // 128 KB
  __shared__ float lMx2[4][256];  // 4 KB per-wave-col row maxes

  int tid = threadIdx.x;
  int lane = tid & 63;
  int w = tid >> 6;
  int qr = w >> 2, qc = w & 3;
  int qd = lane >> 4, fr = lane & 15;

  f32x4 acc[2][2][4][2] = {};

  int srl = w * 16 + (lane >> 3);
  int sslot = lane & 7;

  auto stage = [&](const f16* src, long row0, int kb, int ldsBase) {
#pragma unroll
    for (int k = 0; k < 2; ++k) {
      int rl = srl + k * 8;
      int c = sslot ^ ((rl >> 1) & 7);
      async_ld16(src + (row0 + rl) * (long)D_ + (kb + c * 8),
                 L + ldsBase + (w * 2 + k) * 512 + lane * 8);
    }
  };
  auto iA = [&](int buf, int hh, int t) {
    stage(A, bm + hh * 128, t * 64, buf * 32768 + hh * 8192);
  };
  auto iB = [&](int buf, int hh, int t) {
    stage(Bm, bn + hh * 128, t * 64, buf * 32768 + 16384 + hh * 8192);
  };

  iA(0, 0, 0); iB(0, 0, 0); iB(0, 1, 0); iA(0, 1, 0);

  int cur = 0;
  for (int t = 0; t < 7; ++t) {
    int nxt = cur ^ 1;
    iA(nxt, 0, t + 1);
    QWAIT(6)
    phase_mfma<0, 0>(L, cur, qr, qc, qd, fr, acc);
    iB(nxt, 0, t + 1);
    QWAIT(6)
    phase_mfma<0, 1>(L, cur, qr, qc, qd, fr, acc);
    iB(nxt, 1, t + 1);
    QWAIT(6)
    phase_mfma<1, 0>(L, cur, qr, qc, qd, fr, acc);
    iA(nxt, 1, t + 1);
    QBAR()
    phase_mfma<1, 1>(L, cur, qr, qc, qd, fr, acc);
    cur = nxt;
  }
  QWAIT(4)
  phase_mfma<0, 0>(L, cur, qr, qc, qd, fr, acc);
  QWAIT(2)
  phase_mfma<0, 1>(L, cur, qr, qc, qd, fr, acc);
  QWAIT(0)
  phase_mfma<1, 0>(L, cur, qr, qc, qd, fr, acc);
  QBAR()
  phase_mfma<1, 1>(L, cur, qr, qc, qd, fr, acc);

  // --- PEXP epilogue ---
#pragma unroll
  for (int mh = 0; mh < 2; ++mh)
#pragma unroll
    for (int i = 0; i < 4; ++i)
#pragma unroll
      for (int rl = 0; rl < 4; ++rl) {
        float v = fmaxf(fmaxf(acc[mh][0][i][0][rl], acc[mh][0][i][1][rl]),
                        fmaxf(acc[mh][1][i][0][rl], acc[mh][1][i][1][rl]));
        v = fmaxf(v, __shfl_xor(v, 1, 64));
        v = fmaxf(v, __shfl_xor(v, 2, 64));
        v = fmaxf(v, __shfl_xor(v, 4, 64));
        v = fmaxf(v, __shfl_xor(v, 8, 64));
        if (fr == 0) lMx2[qc][mh * 128 + qr * 64 + i * 16 + qd * 4 + rl] = v;
      }
  __syncthreads();
  if (tid < 256) {
    float ml = fmaxf(fmaxf(lMx2[0][tid], lMx2[1][tid]),
                     fmaxf(lMx2[2][tid], lMx2[3][tid]));
    int cb0 = (bid & 7) * 2;
    Ml[(long)cb0 * S_ + bm + tid] = ml;
    Ml[(long)(cb0 + 1) * S_ + bm + tid] = ml;
  }
#pragma unroll
  for (int mh = 0; mh < 2; ++mh)
#pragma unroll
    for (int i = 0; i < 4; ++i)
#pragma unroll
      for (int rl = 0; rl < 4; ++rl) {
        int rowLoc = mh * 128 + qr * 64 + i * 16 + qd * 4 + rl;
        float ml = fmaxf(fmaxf(lMx2[0][rowLoc], lMx2[1][rowLoc]),
                         fmaxf(lMx2[2][rowLoc], lMx2[3][rowLoc]));
        long row = bm + rowLoc;
#pragma unroll
        for (int nh = 0; nh < 2; ++nh)
#pragma unroll
          for (int j = 0; j < 2; ++j) {
            long col = bn + nh * 128 + qc * 32 + j * 16 + fr;
            C[row * (long)S_ + col] = (f16)__expf(acc[mh][nh][i][j][rl] - ml);
          }
      }
}

// ---------------------------------------------------------------------------
// flash-PV on the 8-phase template (r15-verified, frozen).
// ---------------------------------------------------------------------------
struct PvArgs {
  const f16* S; const float* Ml; const f16* V; f16* C;
  int ldc, zbase, NG;
  long sVz, sCb, sCg;
};

template <int MH>
__device__ inline void pv_phase(const f16* L, int cur, int qr, int qc, int qd,
                                int fr, const f16 (&al)[2][4],
                                f32x4 (&acc)[2][4][2], f32x4 (&lacc)[2][4],
                                f16x8 ones) {
  const f16* Ab = L + cur * 24576 + MH * 8192;
  const f16* Bb = L + cur * 24576 + 16384;
  f16x8 af[4][2], bf[2][2];
#pragma unroll
  for (int i = 0; i < 4; ++i) {
    int rr = qr * 64 + i * 16 + fr;
#pragma unroll
    for (int ks = 0; ks < 2; ++ks) {
      int cc = ks * 4 + qd;
      af[i][ks] = *(const f16x8*)(Ab + ((size_t)rr * 8 + (cc ^ ((rr >> 1) & 7))) * 8);
#pragma unroll
      for (int e = 0; e < 8; ++e) af[i][ks][e] *= al[MH][i];
    }
  }
#pragma unroll
  for (int j = 0; j < 2; ++j) {
    int rr = qc * 32 + j * 16 + fr;
#pragma unroll
    for (int ks = 0; ks < 2; ++ks) {
      int cc = ks * 4 + qd;
      bf[j][ks] = *(const f16x8*)(Bb + ((size_t)rr * 8 + (cc ^ ((rr >> 1) & 7))) * 8);
    }
  }
  __builtin_amdgcn_s_setprio(1);
#pragma unroll
  for (int i = 0; i < 4; ++i) {
    f16x8 a2 = af[i][0] + af[i][1];
    lacc[MH][i] = __builtin_amdgcn_mfma_f32_16x16x32_f16(a2, ones, lacc[MH][i], 0, 0, 0);
#pragma unroll
    for (int j = 0; j < 2; ++j)
#pragma unroll
      for (int ks = 0; ks < 2; ++ks)
        acc[MH][i][j] = __builtin_amdgcn_mfma_f32_16x16x32_f16(
            af[i][ks], bf[j][ks], acc[MH][i][j], 0, 0, 0);
  }
  __builtin_amdgcn_s_setprio(0);
}

__global__ __launch_bounds__(512, 2) void pv_flash8(PvArgs p) {
  int zloc = blockIdx.z;
  int zi = p.zbase + zloc;
  int bb = zi / p.NG; int g = zi - bb * p.NG;
  const f16* Sm = p.S + (long)zloc * S_ * S_;
  const float* MlG = p.Ml + (long)zloc * 16 * S_;
  const f16* V = p.V + (long)zloc * p.sVz;
  f16* C = p.C + bb * p.sCb + g * p.sCg;

  __shared__ f16 L[49152];     // 96 KB: 2 bufs x (A0,A1,B of 8K f16 each)
  __shared__ float lMl[4096];  // 16 KB: [cb][256 rows]

  int tid = threadIdx.x;
  int lane = tid & 63;
  int w = tid >> 6;
  int qr = w >> 2, qc = w & 3;
  int qd = lane >> 4, fr = lane & 15;

  int bid = blockIdx.x;
  long bm = (long)(bid >> 2) * 256;
  long bn = (long)(bid & 3) * 128;

  f32x4 acc[2][4][2] = {};
  f32x4 lacc[2][4] = {};
  f16x8 ones;
#pragma unroll
  for (int e = 0; e < 8; ++e) ones[e] = (f16)1.0f;

  int srl = w * 16 + (lane >> 3);
  int sslot = lane & 7;

  auto stage = [&](const f16* src, long row0, int kb, int ldsBase) {
#pragma unroll
    for (int k = 0; k < 2; ++k) {
      int rl = srl + k * 8;
      int c = sslot ^ ((rl >> 1) & 7);
      async_ld16(src + (row0 + rl) * (long)S_ + (kb + c * 8),
                 L + ldsBase + (w * 2 + k) * 512 + lane * 8);
    }
  };
  auto iA = [&](int buf, int hh, int t) {
    stage(Sm, bm + hh * 128, t * 64, buf * 24576 + hh * 8192);
  };
  auto iB = [&](int buf, int t) {
    stage(V, bn, t * 64, buf * 24576 + 16384);
  };

  // Prologue: stage Ml slab [16 cb][bm..bm+255] into LDS.
  // dest = wave-uniform base (cb*1024B) + lane*16B; row cb = k*8 + w.
#pragma unroll
  for (int k = 0; k < 2; ++k) {
    int cb = k * 8 + w;
    async_ld16(MlG + (long)cb * S_ + bm + lane * 4,
               (char*)lMl + (size_t)cb * 1024 + (size_t)lane * 16);
  }
  iA(0, 0, 0); iB(0, 0); iA(0, 1, 0);
  asm volatile("s_waitcnt vmcnt(6)" ::: "memory");
  __builtin_amdgcn_s_barrier();

  // mg over 16 cb from LDS; al for cb=0.
  float mg[2][4];
  f16 al[2][4];
#pragma unroll
  for (int mh = 0; mh < 2; ++mh)
#pragma unroll
    for (int i = 0; i < 4; ++i) {
      int rloc = mh * 128 + qr * 64 + i * 16 + fr;
      float m = -1e30f;
#pragma unroll
      for (int cb = 0; cb < 16; ++cb)
        m = fmaxf(m, lMl[cb * 256 + rloc]);
      mg[mh][i] = m;
      al[mh][i] = (f16)__expf(lMl[rloc] - m);
    }

  int cur = 0;
  for (int t = 0; t < 31; ++t) {
    int nxt = cur ^ 1;
    if (t && (t & 1) == 0) {
      int cb = t >> 1;
#pragma unroll
      for (int mh = 0; mh < 2; ++mh)
#pragma unroll
        for (int i = 0; i < 4; ++i) {
          int rloc = mh * 128 + qr * 64 + i * 16 + fr;
          al[mh][i] = (f16)__expf(lMl[cb * 256 + rloc] - mg[mh][i]);
        }
    }
    iA(nxt, 0, t + 1);
    QWAIT(4)                     // drains A0(t)+B(t)
    pv_phase<0>(L, cur, qr, qc, qd, fr, al, acc, lacc, ones);
    iB(nxt, t + 1);
    iA(nxt, 1, t + 1);           // B/A1 writes behind ph<0>'s barrier
    QWAIT(6)                     // drains A1(t)
    pv_phase<1>(L, cur, qr, qc, qd, fr, al, acc, lacc, ones);
    cur = nxt;
  }
  {  // t = 31 tail
    int cb = 15;
#pragma unroll
    for (int mh = 0; mh < 2; ++mh)
#pragma unroll
      for (int i = 0; i < 4; ++i) {
        int rloc = mh * 128 + qr * 64 + i * 16 + fr;
        al[mh][i] = (f16)__expf(lMl[cb * 256 + rloc] - mg[mh][i]);
      }
  }
  QWAIT(2)
  pv_phase<0>(L, cur, qr, qc, qd, fr, al, acc, lacc, ones);
  QWAIT(0)
  pv_phase<1>(L, cur, qr, qc, qd, fr, al, acc, lacc, ones);

  int rr0 = qd * 4;
#pragma unroll
  for (int mh = 0; mh < 2; ++mh)
#pragma unroll
    for (int i = 0; i < 4; ++i) {
      float inv[4];
#pragma unroll
      for (int rl = 0; rl < 4; ++rl) inv[rl] = 1.0f / lacc[mh][i][rl];
#pragma unroll
      for (int j = 0; j < 2; ++j)
#pragma unroll
        for (int rl = 0; rl < 4; ++rl) {
          long row = bm + mh * 128 + qr * 64 + i * 16 + rr0 + rl;
          long col = bn + qc * 32 + j * 16 + fr;
          C[row * (long)p.ldc + col] = (f16)(acc[mh][i][j][rl] * inv[rl]);
        }
    }
}

extern "C" void kernel_launch(void* const* d_in, const int* in_sizes, int n_in,
                              void* d_out, int out_size, void* d_ws, size_t ws_size,
                              hipStream_t stream) {
  const float* x  = (const float*)d_in[0];
  const float* Wq = (const float*)d_in[1];
  const float* bq = (const float*)d_in[2];
  const float* Wk = (const float*)d_in[3];
  const float* bk = (const float*)d_in[4];
  const float* Wv = (const float*)d_in[5];
  const float* bv = (const float*)d_in[6];
  const float* Wo = (const float*)d_in[7];
  const float* bo = (const float*)d_in[8];
  float* out = (float*)d_out;

  auto al = [](size_t v) { return (v + 255) & ~(size_t)255; };
  const size_t eX = (size_t)B_ * S_ * D_;
  const size_t eW = (size_t)H_ * D_ * D_;
  const size_t eSS = (size_t)S_ * S_;
  const long SD = (long)S_ * D_;
  const long DD = (long)D_ * D_;
  const long DS = (long)D_ * S_;

  size_t fixed = al(eX * 2) + al(2 * eW * 2) + al(eW * 2) + al(eW * 2)
               + al(2ULL * H_ * D_ * 4);
  int NB = 1, GH = 1, GS = 1; bool found = false;
  for (int nb = 2; nb >= 1 && !found; --nb)
    for (int gh = 8; gh >= 1 && !found; gh >>= 1)
      for (int gs = nb * gh; gs >= 1 && !found; gs >>= 1) {
        size_t need = fixed + al((size_t)nb * S_ * H_ * D_ * 2)
                    + al(2ULL * nb * gh * S_ * D_ * 2)
                    + al((size_t)nb * gh * D_ * S_ * 2)
                    + al(4ULL * nb * SD * 4)
                    + al((size_t)gs * eSS * 2)
                    + al((size_t)gs * 16 * S_ * 4);
        if (need <= ws_size) { NB = nb; GH = gh; GS = gs; found = true; }
      }

  char* p0 = (char*)d_ws;
  size_t off = 0;
  f16* xh    = (f16*)(p0 + off); off += al(eX * 2);
  f16* wqk   = (f16*)(p0 + off); off += al(2 * eW * 2);
  f16* wv    = (f16*)(p0 + off); off += al(eW * 2);
  f16* wo    = (f16*)(p0 + off); off += al(eW * 2);
  float* bqk = (float*)(p0 + off); off += al(2ULL * H_ * D_ * 4);
  f16* catb  = (f16*)(p0 + off); off += al((size_t)NB * S_ * H_ * D_ * 2);
  f16* qk    = (f16*)(p0 + off); off += al(2ULL * NB * GH * S_ * D_ * 2);
  f16* vT    = (f16*)(p0 + off); off += al((size_t)NB * GH * D_ * S_ * 2);
  float* opart = (float*)(p0 + off); off += al(4ULL * NB * SD * 4);
  f16* scores = (f16*)(p0 + off); off += al((size_t)GS * eSS * 2);
  float* mloc = (float*)(p0 + off);

  // ---- prep ----
  cvt_f16<<<dim3((unsigned)((eX + 255) / 256)), 256, 0, stream>>>(x, xh, (long)eX);
  dim3 tb(32, 8, 1);
  transpose_f32<<<dim3(16, 16, H_), tb, 0, stream>>>(Wq, wqk, D_, D_);
  transpose_f32<<<dim3(16, 16, H_), tb, 0, stream>>>(Wk, wqk + eW, D_, D_);
  transpose_f32<<<dim3(16, 16, H_), tb, 0, stream>>>(Wv, wv, D_, D_);
  transpose_f32<<<dim3(16, 128, 1), tb, 0, stream>>>(Wo, wo, H_ * D_, D_);
  hipMemcpyAsync(bqk, bq, (size_t)H_ * D_ * 4, hipMemcpyDeviceToDevice, stream);
  hipMemcpyAsync(bqk + H_ * D_, bk, (size_t)H_ * D_ * 4, hipMemcpyDeviceToDevice, stream);

  for (int b0 = 0; b0 < B_; b0 += NB) {
    for (int h0 = 0; h0 < H_; h0 += GH) {
      if (NB == 2 && GH == 8) {
        QkvArgs a{xh, wqk, wv, qk, vT, bqk, bv};
        qkv_proj8<<<dim3(16, 1, 48), 512, 0, stream>>>(a);
      } else {
        {  // Q+K projections
          GemmArgs a{};
          a.A = xh + (long)b0 * SD;
          a.Bm = wqk + (long)h0 * DD;
          a.C = qk; a.bias = bqk + (long)h0 * D_;
          a.K = D_; a.lda = D_; a.ldb = D_; a.ldc = D_;
          a.zbase = 0; a.NG = GH; a.PBG = NB * GH;
          a.sAb = SD;
          a.sBp = (long)H_ * DD; a.sBg = DD;
          a.sCz = SD;
          a.sbp = (long)H_ * D_; a.sbg = D_;
          gemm_nt<f16, 1, false><<<dim3(4, 16, 2 * NB * GH), 256, 0, stream>>>(a);
        }
        {  // V^T
          GemmArgs a{};
          a.A = wv + (long)h0 * DD; a.Bm = xh + (long)b0 * SD;
          a.C = vT; a.bias = bv + (long)h0 * D_;
          a.K = D_; a.lda = D_; a.ldb = D_; a.ldc = S_;
          a.zbase = 0; a.NG = GH; a.PBG = NB * GH;
          a.sAg = DD;
          a.sBb = SD;
          a.sCz = DS;
          a.sbg = D_;
          gemm_nt<f16, 2, false><<<dim3(16, 4, NB * GH), 256, 0, stream>>>(a);
        }
      }
      for (int g0 = 0; g0 < NB * GH; g0 += GS) {
        {  // scores -> P = exp(s - ml256) f16, Mloc (8-phase template)
          Sc8Args a{qk + (long)g0 * SD, qk + ((long)NB * GH + g0) * SD,
                    scores, mloc};
          scores8<<<dim3(64, 1, GS), 512, 0, stream>>>(a);
        }
        {  // flash PV on the 8-phase template (256x128, 32-tile pipeline)
          PvArgs a{};
          a.S = scores; a.Ml = mloc; a.V = vT + (long)g0 * DS;
          a.C = catb + (long)h0 * D_;
          a.ldc = H_ * D_; a.zbase = g0; a.NG = GH;
          a.sVz = DS; a.sCb = (long)S_ * H_ * D_; a.sCg = D_;
          pv_flash8<<<dim3(32, 1, GS), 512, 0, stream>>>(a);
        }
      }
    }
    {  // out-proj split-K (4 slabs of 1024)
      GemmArgs a{};
      a.A = catb; a.Bm = wo;
      a.C = opart;
      a.K = 1024; a.lda = H_ * D_; a.ldb = H_ * D_; a.ldc = D_;
      a.zbase = 0; a.NG = 4; a.PBG = NB * 4;
      a.sAb = (long)S_ * H_ * D_; a.sAg = 1024;
      a.sBg = 1024;
      a.sCb = SD; a.sCg = (long)NB * SD;
      gemm_nt<float, 0, false><<<dim3(4, 16, NB * 4), 256, 0, stream>>>(a);
    }
    reduce_out<<<dim3((unsigned)(((long)NB * SD + 255) / 256)), 256, 0, stream>>>(
        opart, bo, out + (long)b0 * SD, (long)NB * SD, 4);
  }
}